// Round 8
// baseline (670.270 us; speedup 1.0000x reference)
//
#include <hip/hip_runtime.h>
#include <math.h>

#define D 128
#define NF 10
#define N_IP 20000
#define N_CONN 100000
#define NE 200000
#define T_ROUNDS 3

typedef unsigned short u16;
using bf16x8 = __attribute__((ext_vector_type(8))) short;
using floatx4 = __attribute__((ext_vector_type(4))) float;

__device__ inline u16 f2bf(float f) {
  union { float f; unsigned u; } v; v.f = f;
  unsigned u = v.u;
  return (u16)((u + 0x7fffu + ((u >> 16) & 1u)) >> 16);  // RNE
}
__device__ inline float bf2f(u16 h) {
  union { unsigned u; float f; } v; v.u = ((unsigned)h) << 16; return v.f;
}

__device__ inline float fsigmoid(float s) { return 1.f / (1.f + __expf(-s)); }
__device__ inline float ftanh(float a) {
  a = fminf(fmaxf(a, -15.f), 15.f);
  float e = __expf(2.f * a);
  return (e - 1.f) / (e + 1.f);
}

// ---------------- fused init: states + cnt zero ----------------
__global__ void k_init_all(u16* __restrict__ ip_state, u16* __restrict__ conn_state,
                           const float* __restrict__ feat, int* __restrict__ cnt) {
  int i = blockIdx.x * blockDim.x + threadIdx.x;
  const int nip = N_IP * D;
  const int nstate = (N_IP + N_CONN) * D;
  if (i < nip) {
    ip_state[i] = 0x3F80;  // bf16(1.0)
  } else if (i < nstate) {
    int j = i - nip;
    int r = j >> 7, c = j & 127;
    conn_state[j] = (c < NF) ? f2bf(feat[r * NF + c]) : (u16)0;
  }
  if (i < N_CONN + N_IP) cnt[i] = 0;
}

// ---------------- fused weight prep (all matrices, bf16 [col][k]) ----------------
__global__ void k_prep_all(
    const float* __restrict__ gik, const float* __restrict__ gir,
    const float* __restrict__ gck, const float* __restrict__ gcr,
    const float* __restrict__ Wm1, const float* __restrict__ Wm2,
    const float* __restrict__ Wr1, const float* __restrict__ Wr2,
    u16* __restrict__ gikb, u16* __restrict__ girb,
    u16* __restrict__ gckb, u16* __restrict__ gcrb,
    u16* __restrict__ wm1b, u16* __restrict__ wm2b,
    u16* __restrict__ wm1t, u16* __restrict__ wm2t,
    u16* __restrict__ wr1b, u16* __restrict__ wr2b) {
  int i = blockIdx.x * blockDim.x + threadIdx.x;
  if (i < 196608) {  // 4 GRU mats (128x384 -> [col][k] 384x128)
    int m = i / 49152, r = i % 49152;
    const float* W = (m == 0) ? gik : (m == 1) ? gir : (m == 2) ? gck : gcr;
    u16* Wb = (m == 0) ? gikb : (m == 1) ? girb : (m == 2) ? gckb : gcrb;
    int col = r >> 7, k = r & 127;
    Wb[r] = f2bf(W[k * 384 + col]);
  } else if (i < 278528) {  // 5 x 128x128 blocks
    int j = i - 196608;
    int m = j / 16384, r = j % 16384;
    const float* W; u16* Wb; int k0;
    if (m == 0) { W = Wm1; Wb = wm1b; k0 = 128; }
    else if (m == 1) { W = Wm2; Wb = wm2b; k0 = 128; }
    else if (m == 2) { W = Wm1; Wb = wm1t; k0 = 0; }
    else if (m == 3) { W = Wm2; Wb = wm2t; k0 = 0; }
    else { W = Wr1; Wb = wr1b; k0 = 0; }
    int col = r >> 7, k = r & 127;
    Wb[r] = f2bf(W[(k0 + k) * 128 + col]);
  } else if (i < 286720) {  // Wr2 128x64 -> [col][k] 64x128
    int r = i - 278528;
    int col = r >> 7, k = r & 127;
    wr2b[r] = f2bf(Wr2[k * 64 + col]);
  }
}

__global__ void k_count(const int* __restrict__ d1, const int* __restrict__ d2,
                        int* __restrict__ c1, int* __restrict__ c2) {
  int e = blockIdx.x * blockDim.x + threadIdx.x;
  if (e >= NE) return;
  atomicAdd(&c1[d1[e]], 1);
  atomicAdd(&c2[d2[e]], 1);
}

// ---------------- merged 3-pass exclusive scan (both segment arrays) ----------------
__global__ void k_scan_part2(const int* __restrict__ cnt1, int* __restrict__ bsum1,
                             int n1, int nb1,
                             const int* __restrict__ cnt2, int* __restrict__ bsum2, int n2) {
  const int* cnt; int* bsum; int n, b;
  if ((int)blockIdx.x < nb1) { cnt = cnt1; bsum = bsum1; n = n1; b = blockIdx.x; }
  else { cnt = cnt2; bsum = bsum2; n = n2; b = blockIdx.x - nb1; }
  int t = threadIdx.x;
  int base = b * 1024 + t * 4;
  int s = 0;
#pragma unroll
  for (int i = 0; i < 4; i++) { int j = base + i; if (j < n) s += cnt[j]; }
  for (int d = 32; d > 0; d >>= 1) s += __shfl_xor(s, d, 64);
  __shared__ int wred[4];
  int lane = t & 63, wv = t >> 6;
  if (lane == 0) wred[wv] = s;
  __syncthreads();
  if (t == 0) bsum[b] = wred[0] + wred[1] + wred[2] + wred[3];
}

__device__ inline void scan_mid_body(int* bsum, int m, int t) {
  int v = (t < m) ? bsum[t] : 0;
  int lane = t & 63, wv = t >> 6;
  int x = v;
  for (int d = 1; d < 64; d <<= 1) { int y = __shfl_up(x, d, 64); if (lane >= d) x += y; }
  __shared__ int wsum[4];
  if (lane == 63) wsum[wv] = x;
  __syncthreads();
  int add = 0;
  for (int i = 0; i < wv; i++) add += wsum[i];
  int ex = add + x - v;
  if (t < m) bsum[t] = ex;
  __syncthreads();
}

__global__ void k_scan_mid2(int* __restrict__ bsum1, int m1, int* __restrict__ bsum2, int m2) {
  int t = threadIdx.x;
  scan_mid_body(bsum1, m1, t);
  scan_mid_body(bsum2, m2, t);
}

__global__ void k_scan_final2(const int* __restrict__ cnt1, const int* __restrict__ bsum1,
                              int* __restrict__ off1, int n1, int nb1,
                              const int* __restrict__ cnt2, const int* __restrict__ bsum2,
                              int* __restrict__ off2, int n2) {
  const int* cnt; const int* bsum; int* off; int n, b;
  if ((int)blockIdx.x < nb1) { cnt = cnt1; bsum = bsum1; off = off1; n = n1; b = blockIdx.x; }
  else { cnt = cnt2; bsum = bsum2; off = off2; n = n2; b = blockIdx.x - nb1; }
  int t = threadIdx.x;
  int base = b * 1024 + t * 4;
  int vals[4]; int s = 0;
#pragma unroll
  for (int i = 0; i < 4; i++) {
    int j = base + i;
    vals[i] = (j < n) ? cnt[j] : 0;
    s += vals[i];
  }
  int lane = t & 63, wv = t >> 6;
  int x = s;
  for (int d = 1; d < 64; d <<= 1) { int y = __shfl_up(x, d, 64); if (lane >= d) x += y; }
  __shared__ int wsum[4];
  if (lane == 63) wsum[wv] = x;
  __syncthreads();
  int add = 0;
  for (int i = 0; i < wv; i++) add += wsum[i];
  int run = add + x - s + bsum[b];
#pragma unroll
  for (int i = 0; i < 4; i++) {
    int j = base + i;
    if (j < n) off[j] = run;
    run += vals[i];
  }
}

__global__ void k_copyint(const int* __restrict__ a, int* __restrict__ b, int n) {
  int i = blockIdx.x * blockDim.x + threadIdx.x;
  if (i < n) b[i] = a[i];
}

__global__ void k_scatter(const int* __restrict__ s1, const int* __restrict__ d1,
                          const int* __restrict__ s2, const int* __restrict__ d2,
                          int* __restrict__ cur1, int* __restrict__ cur2,
                          int* __restrict__ o1, int* __restrict__ o2) {
  int e = blockIdx.x * blockDim.x + threadIdx.x;
  if (e >= NE) return;
  int p1 = atomicAdd(&cur1[d1[e]], 1);
  o1[p1] = s1[e];
  int p2 = atomicAdd(&cur2[d2[e]], 1);
  o2[p2] = s2[e];
}

// ---------------- merged P-GEMM (bf16 in/out): P = S @ Wt^T ----------------
__global__ __launch_bounds__(256) void k_gemmP(
    const u16* __restrict__ S1, const u16* __restrict__ Wt1, u16* __restrict__ P1,
    int M1, int tiles1,
    const u16* __restrict__ S2, const u16* __restrict__ Wt2, u16* __restrict__ P2,
    int M2) {
  __shared__ __align__(16) u16 Wls[128 * 128];  // 32KB; reused as C (64x136)
  const u16* S; const u16* Wt; u16* P; int M, bm;
  if ((int)blockIdx.x < tiles1) { S = S1; Wt = Wt1; P = P1; M = M1; bm = blockIdx.x * 64; }
  else { S = S2; Wt = Wt2; P = P2; M = M2; bm = (blockIdx.x - tiles1) * 64; }
  const int tid = threadIdx.x, wv = tid >> 6, lane = tid & 63;
  const int lrow = lane & 15, quad = lane >> 4;
#pragma unroll
  for (int i = 0; i < 8; i++) {  // stage W swizzled
    int task = i * 256 + tid;
    int col = task >> 4, gr = task & 15;
    uint4 v = *(const uint4*)(Wt + (size_t)col * 128 + gr * 8);
    *(uint4*)(Wls + (size_t)col * 128 + ((gr ^ (col & 15)) * 8)) = v;
  }
  const int arow = bm + wv * 16 + lrow;
  const bool arv = arow < M;
  const bf16x8 zv = {0, 0, 0, 0, 0, 0, 0, 0};
  bf16x8 a[4];
#pragma unroll
  for (int ks = 0; ks < 4; ks++)
    a[ks] = arv ? *(const bf16x8*)(S + (size_t)arow * 128 + quad * 8 + ks * 32) : zv;
  __syncthreads();
  floatx4 acc[8];
#pragma unroll
  for (int ct = 0; ct < 8; ct++) acc[ct] = {0.f, 0.f, 0.f, 0.f};
#pragma unroll
  for (int ks = 0; ks < 4; ks++) {
#pragma unroll
    for (int ct = 0; ct < 8; ct++) {
      int col = ct * 16 + lrow;
      bf16x8 b = *(const bf16x8*)(Wls + (size_t)col * 128 + (((4 * ks + quad) ^ lrow) * 8));
      acc[ct] = __builtin_amdgcn_mfma_f32_16x16x32_bf16(a[ks], b, acc[ct], 0, 0, 0);
    }
  }
  __syncthreads();  // W reads done; reuse as C
  u16* Cls = Wls;   // 64 x 136
#pragma unroll
  for (int ct = 0; ct < 8; ct++) {
    int col = ct * 16 + lrow;
#pragma unroll
    for (int reg = 0; reg < 4; reg++) {
      int lr = wv * 16 + quad * 4 + reg;
      Cls[(size_t)lr * 136 + col] = f2bf(acc[ct][reg]);
    }
  }
  __syncthreads();
#pragma unroll
  for (int i = 0; i < 4; i++) {  // coalesced bf16 write-out
    int task = i * 256 + tid;
    int row = task >> 4, c8 = task & 15;
    int gr2 = bm + row;
    if (gr2 < M)
      *(uint4*)(P + (size_t)gr2 * 128 + c8 * 8) = *(const uint4*)(Cls + (size_t)row * 136 + c8 * 8);
  }
}

// ---------------- merged fused Q-GEMM + gather-mean (bf16 in/out) ----------------
__global__ __launch_bounds__(256) void k_qgather(
    const u16* __restrict__ S1, const u16* __restrict__ Wb1, const float* __restrict__ bias1,
    const u16* __restrict__ P1g, const int* __restrict__ srcs1g,
    const int* __restrict__ off1g, const int* __restrict__ cnt1g,
    u16* __restrict__ out1, int n1, int tiles1,
    const u16* __restrict__ S2, const u16* __restrict__ Wb2, const float* __restrict__ bias2,
    const u16* __restrict__ P2g, const int* __restrict__ srcs2g,
    const int* __restrict__ off2g, const int* __restrict__ cnt2g,
    u16* __restrict__ out2, int n2) {
  __shared__ __align__(16) char smem[64 * 132 * 4];  // 33792 B
  u16* Wls = (u16*)smem;
  float* Qls = (float*)smem;
  const u16* S; const u16* Wb; const float* bias; const u16* P;
  const int* srcs; const int* off; const int* cnt; u16* outm; int nnodes, bm;
  if ((int)blockIdx.x < tiles1) {
    S = S1; Wb = Wb1; bias = bias1; P = P1g; srcs = srcs1g; off = off1g; cnt = cnt1g;
    outm = out1; nnodes = n1; bm = blockIdx.x * 64;
  } else {
    S = S2; Wb = Wb2; bias = bias2; P = P2g; srcs = srcs2g; off = off2g; cnt = cnt2g;
    outm = out2; nnodes = n2; bm = (blockIdx.x - tiles1) * 64;
  }
  const int tid = threadIdx.x, wv = tid >> 6, lane = tid & 63;
  const int lrow = lane & 15, quad = lane >> 4;
#pragma unroll
  for (int i = 0; i < 8; i++) {  // stage W swizzled
    int task = i * 256 + tid;
    int col = task >> 4, gr = task & 15;
    uint4 v = *(const uint4*)(Wb + (size_t)col * 128 + gr * 8);
    *(uint4*)(Wls + (size_t)col * 128 + ((gr ^ (col & 15)) * 8)) = v;
  }
  const int arow = bm + wv * 16 + lrow;
  const bool arv = arow < nnodes;
  const bf16x8 zv = {0, 0, 0, 0, 0, 0, 0, 0};
  bf16x8 a[4];
#pragma unroll
  for (int ks = 0; ks < 4; ks++)
    a[ks] = arv ? *(const bf16x8*)(S + (size_t)arow * 128 + quad * 8 + ks * 32) : zv;
  __syncthreads();
  floatx4 acc[8];
#pragma unroll
  for (int ct = 0; ct < 8; ct++) acc[ct] = {0.f, 0.f, 0.f, 0.f};
#pragma unroll
  for (int ks = 0; ks < 4; ks++) {
#pragma unroll
    for (int ct = 0; ct < 8; ct++) {
      int col = ct * 16 + lrow;
      bf16x8 b = *(const bf16x8*)(Wls + (size_t)col * 128 + (((4 * ks + quad) ^ lrow) * 8));
      acc[ct] = __builtin_amdgcn_mfma_f32_16x16x32_bf16(a[ks], b, acc[ct], 0, 0, 0);
    }
  }
  __syncthreads();  // W reads done; reuse smem as Q (fp32, stride 132)
#pragma unroll
  for (int ct = 0; ct < 8; ct++) {
    int col = ct * 16 + lrow;
    float bv = bias[col];
#pragma unroll
    for (int reg = 0; reg < 4; reg++) {
      int lr = wv * 16 + quad * 4 + reg;
      Qls[(size_t)lr * 132 + col] = acc[ct][reg] + bv;
    }
  }
  __syncthreads();
  // gather: 64 nodes x 16 col-granules (8 bf16 each) = 1024 tasks
#pragma unroll
  for (int it = 0; it < 4; it++) {
    int task = it * 256 + tid;
    int nl = task >> 4, c8 = (task & 15) << 3;
    int node = bm + nl;
    if (node >= nnodes) continue;
    const float* qp = Qls + (size_t)nl * 132 + c8;
    float4 qa = *(const float4*)(qp);
    float4 qb = *(const float4*)(qp + 4);
    float q[8] = {qa.x, qa.y, qa.z, qa.w, qb.x, qb.y, qb.z, qb.w};
    float acg[8] = {0.f, 0.f, 0.f, 0.f, 0.f, 0.f, 0.f, 0.f};
    int o = off[node], n = cnt[node];
    int i = 0;
    for (; i + 4 <= n; i += 4) {
      int s0 = srcs[o + i], s1 = srcs[o + i + 1], s2 = srcs[o + i + 2], s3 = srcs[o + i + 3];
      uint4 v0 = *(const uint4*)(P + (size_t)s0 * 128 + c8);
      uint4 v1 = *(const uint4*)(P + (size_t)s1 * 128 + c8);
      uint4 v2 = *(const uint4*)(P + (size_t)s2 * 128 + c8);
      uint4 v3 = *(const uint4*)(P + (size_t)s3 * 128 + c8);
      unsigned w[16] = {v0.x, v0.y, v0.z, v0.w, v1.x, v1.y, v1.z, v1.w,
                        v2.x, v2.y, v2.z, v2.w, v3.x, v3.y, v3.z, v3.w};
#pragma unroll
      for (int e = 0; e < 4; e++)
#pragma unroll
        for (int k = 0; k < 4; k++) {
          unsigned ww = w[e * 4 + k];
          float lo = __uint_as_float(ww << 16);
          float hi = __uint_as_float(ww & 0xffff0000u);
          acg[2 * k] += fmaxf(lo + q[2 * k], 0.f);
          acg[2 * k + 1] += fmaxf(hi + q[2 * k + 1], 0.f);
        }
    }
    for (; i < n; i++) {
      int s0 = srcs[o + i];
      uint4 v0 = *(const uint4*)(P + (size_t)s0 * 128 + c8);
      unsigned w[4] = {v0.x, v0.y, v0.z, v0.w};
#pragma unroll
      for (int k = 0; k < 4; k++) {
        unsigned ww = w[k];
        float lo = __uint_as_float(ww << 16);
        float hi = __uint_as_float(ww & 0xffff0000u);
        acg[2 * k] += fmaxf(lo + q[2 * k], 0.f);
        acg[2 * k + 1] += fmaxf(hi + q[2 * k + 1], 0.f);
      }
    }
    float inv = 1.f / fmaxf((float)n, 1.f);
    bf16x8 ov;
#pragma unroll
    for (int k = 0; k < 8; k++) ov[k] = (short)f2bf(acg[k] * inv);
    *(bf16x8*)(outm + (size_t)node * 128 + c8) = ov;
  }
}

// ---------------- merged fused GRU v5: 128 rows/block, 16-col chunks (24.6KB LDS) ----------------
// 8 chunks x (stage 24KB from L2 -> 48 MFMA -> epilogue). __launch_bounds__(256,4)
// targets 4 blocks/CU (vs 2 at 49KB) to hide the staging/barrier latency.
__global__ __launch_bounds__(256, 4) void k_gru_fused(
    const u16* __restrict__ X1, const u16* __restrict__ Wx1, const u16* __restrict__ Wh1,
    const float* __restrict__ b1, u16* __restrict__ H1, int r1, int tiles1,
    const u16* __restrict__ X2, const u16* __restrict__ Wx2, const u16* __restrict__ Wh2,
    const float* __restrict__ b2, u16* __restrict__ H2, int r2) {
  __shared__ __align__(16) u16 Ls[6 * 16 * 128];  // 24576 B
  const u16* X; const u16* Wxb; const u16* Whb; const float* bias; u16* H;
  int rows, bm;
  if ((int)blockIdx.x < tiles1) {
    X = X1; Wxb = Wx1; Whb = Wh1; bias = b1; H = H1; rows = r1; bm = blockIdx.x * 128;
  } else {
    X = X2; Wxb = Wx2; Whb = Wh2; bias = b2; H = H2; rows = r2;
    bm = (blockIdx.x - tiles1) * 128;
  }
  const int tid = threadIdx.x, wv = tid >> 6, lane = tid & 63;
  const int lrow = lane & 15, quad = lane >> 4;
  const bf16x8 zv = {0, 0, 0, 0, 0, 0, 0, 0};
  bf16x8 ax[2][4], ah[2][4];
#pragma unroll
  for (int tile = 0; tile < 2; tile++) {
    int arow = bm + tile * 64 + wv * 16 + lrow;
    bool arv = arow < rows;
    const u16* xp = X + (size_t)arow * 128 + quad * 8;
    const u16* hp = H + (size_t)arow * 128 + quad * 8;
#pragma unroll
    for (int ks = 0; ks < 4; ks++) {
      ax[tile][ks] = arv ? *(const bf16x8*)(xp + ks * 32) : zv;
      ah[tile][ks] = arv ? *(const bf16x8*)(hp + ks * 32) : zv;
    }
  }
  for (int ch = 0; ch < 8; ch++) {
    __syncthreads();  // prev chunk's LDS readers done
    // stage: 6 segs x 16 cols x 16 granules = 1536 uint4 tasks (6/thread)
    {
      uint4 v[6];
#pragma unroll
      for (int j = 0; j < 6; j++) {
        int task = j * 256 + tid;
        int seg = task >> 8, rem = task & 255;
        int col = rem >> 4, gr = rem & 15;
        const u16* gsrc = (seg < 3 ? Wxb : Whb) +
                          (size_t)((seg < 3 ? seg : seg - 3) * 128 + ch * 16 + col) * 128 + gr * 8;
        v[j] = *(const uint4*)gsrc;
      }
#pragma unroll
      for (int j = 0; j < 6; j++) {
        int task = j * 256 + tid;
        int seg = task >> 8, rem = task & 255;
        int col = rem >> 4, gr = rem & 15;
        *(uint4*)(Ls + (size_t)(seg * 16 + col) * 128 + ((gr ^ col) * 8)) = v[j];
      }
    }
    __syncthreads();
    floatx4 acc[2][3][2];  // tile, gate, x/h -> 48 VGPRs
#pragma unroll
    for (int tile = 0; tile < 2; tile++)
#pragma unroll
      for (int g = 0; g < 3; g++) {
        acc[tile][g][0] = {0.f, 0.f, 0.f, 0.f};
        acc[tile][g][1] = {0.f, 0.f, 0.f, 0.f};
      }
#pragma unroll
    for (int ks = 0; ks < 4; ks++) {
      int posu = ((4 * ks + quad) ^ lrow) * 8;
#pragma unroll
      for (int g = 0; g < 3; g++) {
        bf16x8 bx = *(const bf16x8*)(Ls + (size_t)(g * 16 + lrow) * 128 + posu);
        bf16x8 bh = *(const bf16x8*)(Ls + (size_t)((3 + g) * 16 + lrow) * 128 + posu);
        acc[0][g][0] = __builtin_amdgcn_mfma_f32_16x16x32_bf16(ax[0][ks], bx, acc[0][g][0], 0, 0, 0);
        acc[0][g][1] = __builtin_amdgcn_mfma_f32_16x16x32_bf16(ah[0][ks], bh, acc[0][g][1], 0, 0, 0);
        acc[1][g][0] = __builtin_amdgcn_mfma_f32_16x16x32_bf16(ax[1][ks], bx, acc[1][g][0], 0, 0, 0);
        acc[1][g][1] = __builtin_amdgcn_mfma_f32_16x16x32_bf16(ah[1][ks], bh, acc[1][g][1], 0, 0, 0);
      }
    }
    int hcol = ch * 16 + lrow;
    float bxz = bias[hcol];
    float bxr = bias[128 + hcol];
    float bxh = bias[256 + hcol];
    float bhz = bias[384 + hcol];
    float bhr = bias[384 + 128 + hcol];
    float bhh = bias[384 + 256 + hcol];
#pragma unroll
    for (int tile = 0; tile < 2; tile++) {
#pragma unroll
      for (int reg = 0; reg < 4; reg++) {
        int r = bm + tile * 64 + wv * 16 + quad * 4 + reg;
        if (r < rows) {
          float xz = acc[tile][0][0][reg] + bxz;
          float xr = acc[tile][1][0][reg] + bxr;
          float xh = acc[tile][2][0][reg] + bxh;
          float hz = acc[tile][0][1][reg] + bhz;
          float hr = acc[tile][1][1][reg] + bhr;
          float hh = acc[tile][2][1][reg] + bhh;
          float z = fsigmoid(xz + hz);
          float rr = fsigmoid(xr + hr);
          float hc = ftanh(xh + rr * hh);
          u16* hp2 = H + (size_t)r * 128 + hcol;
          float hold = bf2f(*hp2);
          *hp2 = f2bf(z * hold + (1.f - z) * hc);
        }
      }
    }
  }
}

// ---------------- fully fused readout: 2 GEMMs + logits + softmax ----------------
__global__ __launch_bounds__(256) void k_readout2(
    const u16* __restrict__ S, const u16* __restrict__ W1b, const float* __restrict__ b1,
    const u16* __restrict__ W2b, const float* __restrict__ b2,
    const float* __restrict__ W3, const float* __restrict__ b3,
    float* __restrict__ out, int M) {
  __shared__ __align__(16) char smem[64 * 132 * 4];  // 33792 B
  u16* Wls = (u16*)smem;                 // phase1: W1 32KB swizzled
  u16* H1ls = (u16*)smem;                // phase2/3: 64 x 136 u16
  u16* W2ls = (u16*)(smem + 17408);      // 64 x 128 u16
  u16* H2ls = (u16*)smem;                // phase4/5: 64 x 72 u16
  float* W3ls = (float*)(smem + 9216);
  float* b3ls = (float*)(smem + 9216 + 3840);
  const int tid = threadIdx.x, wv = tid >> 6, lane = tid & 63;
  const int lrow = lane & 15, quad = lane >> 4;
  const int bm = blockIdx.x * 64;
#pragma unroll
  for (int i = 0; i < 8; i++) {
    int task = i * 256 + tid;
    int col = task >> 4, gr = task & 15;
    uint4 v = *(const uint4*)(W1b + (size_t)col * 128 + gr * 8);
    *(uint4*)(Wls + (size_t)col * 128 + ((gr ^ (col & 15)) * 8)) = v;
  }
  const int arow = bm + wv * 16 + lrow;
  const bool arv = arow < M;
  const bf16x8 zv = {0, 0, 0, 0, 0, 0, 0, 0};
  bf16x8 a[4];
#pragma unroll
  for (int ks = 0; ks < 4; ks++)
    a[ks] = arv ? *(const bf16x8*)(S + (size_t)arow * 128 + quad * 8 + ks * 32) : zv;
  __syncthreads();
  floatx4 acc1[8];
#pragma unroll
  for (int ct = 0; ct < 8; ct++) acc1[ct] = {0.f, 0.f, 0.f, 0.f};
#pragma unroll
  for (int ks = 0; ks < 4; ks++) {
#pragma unroll
    for (int ct = 0; ct < 8; ct++) {
      int col = ct * 16 + lrow;
      bf16x8 b = *(const bf16x8*)(Wls + (size_t)col * 128 + (((4 * ks + quad) ^ lrow) * 8));
      acc1[ct] = __builtin_amdgcn_mfma_f32_16x16x32_bf16(a[ks], b, acc1[ct], 0, 0, 0);
    }
  }
  __syncthreads();
#pragma unroll
  for (int ct = 0; ct < 8; ct++) {
    int col = ct * 16 + lrow;
    float bv = b1[col];
#pragma unroll
    for (int reg = 0; reg < 4; reg++) {
      int lr = wv * 16 + quad * 4 + reg;
      H1ls[(size_t)lr * 136 + col] = f2bf(fmaxf(acc1[ct][reg] + bv, 0.f));
    }
  }
#pragma unroll
  for (int i = 0; i < 4; i++) {
    int task = i * 256 + tid;
    int col = task >> 4, gr = task & 15;
    uint4 v = *(const uint4*)(W2b + (size_t)col * 128 + gr * 8);
    *(uint4*)(W2ls + (size_t)col * 128 + ((gr ^ (col & 15)) * 8)) = v;
  }
  __syncthreads();
  bf16x8 a2[4];
#pragma unroll
  for (int ks = 0; ks < 4; ks++)
    a2[ks] = *(const bf16x8*)(H1ls + (size_t)(wv * 16 + lrow) * 136 + quad * 8 + ks * 32);
  floatx4 acc2[4];
#pragma unroll
  for (int ct = 0; ct < 4; ct++) acc2[ct] = {0.f, 0.f, 0.f, 0.f};
#pragma unroll
  for (int ks = 0; ks < 4; ks++) {
#pragma unroll
    for (int ct = 0; ct < 4; ct++) {
      int col = ct * 16 + lrow;
      bf16x8 b = *(const bf16x8*)(W2ls + (size_t)col * 128 + (((4 * ks + quad) ^ lrow) * 8));
      acc2[ct] = __builtin_amdgcn_mfma_f32_16x16x32_bf16(a2[ks], b, acc2[ct], 0, 0, 0);
    }
  }
  __syncthreads();
#pragma unroll
  for (int ct = 0; ct < 4; ct++) {
    int col = ct * 16 + lrow;
    float bv = b2[col];
#pragma unroll
    for (int reg = 0; reg < 4; reg++) {
      int lr = wv * 16 + quad * 4 + reg;
      H2ls[(size_t)lr * 72 + col] = f2bf(fmaxf(acc2[ct][reg] + bv, 0.f));
    }
  }
  for (int l = tid; l < 960; l += 256) W3ls[l] = W3[l];
  if (tid < 15) b3ls[tid] = b3[tid];
  __syncthreads();
  if (tid < 64) {
    int row = tid, gr2 = bm + row;
    if (gr2 < M) {
      float lg[15];
#pragma unroll
      for (int c = 0; c < 15; c++) lg[c] = b3ls[c];
      for (int k = 0; k < 64; k++) {
        float hk = bf2f(H2ls[(size_t)row * 72 + k]);
#pragma unroll
        for (int c = 0; c < 15; c++) lg[c] += hk * W3ls[k * 15 + c];
      }
      float m = lg[0];
#pragma unroll
      for (int c = 1; c < 15; c++) m = fmaxf(m, lg[c]);
      float ssum = 0.f;
#pragma unroll
      for (int c = 0; c < 15; c++) { lg[c] = __expf(lg[c] - m); ssum += lg[c]; }
      float inv = 1.f / ssum;
#pragma unroll
      for (int c = 0; c < 15; c++) out[(size_t)gr2 * 15 + c] = lg[c] * inv;
    }
  }
}

// ---------------- launch ----------------
extern "C" void kernel_launch(void* const* d_in, const int* in_sizes, int n_in,
                              void* d_out, int out_size, void* d_ws, size_t ws_size,
                              hipStream_t stream) {
  const float* feat = (const float*)d_in[0];
  const int* src1 = (const int*)d_in[1];
  const int* dst1 = (const int*)d_in[2];
  const int* src2 = (const int*)d_in[3];
  const int* dst2 = (const int*)d_in[4];
  const float* Wm1 = (const float*)d_in[5];
  const float* bm1 = (const float*)d_in[6];
  const float* Wm2 = (const float*)d_in[7];
  const float* bm2 = (const float*)d_in[8];
  const float* gik = (const float*)d_in[9];
  const float* gir = (const float*)d_in[10];
  const float* gib = (const float*)d_in[11];
  const float* gck = (const float*)d_in[12];
  const float* gcr = (const float*)d_in[13];
  const float* gcb = (const float*)d_in[14];
  const float* Wr1 = (const float*)d_in[15];
  const float* br1 = (const float*)d_in[16];
  const float* Wr2 = (const float*)d_in[17];
  const float* br2 = (const float*)d_in[18];
  const float* Wr3 = (const float*)d_in[19];
  const float* br3 = (const float*)d_in[20];
  float* out = (float*)d_out;

  // ---- workspace layout (u16 units) ----
  u16* w16 = (u16*)d_ws;
  size_t o = 0;
  u16* ip_state = w16 + o;   o += (size_t)N_IP * D;
  u16* conn_state = w16 + o; o += (size_t)N_CONN * D;
  u16* sum1 = w16 + o;       o += (size_t)N_CONN * D;
  u16* sum2 = w16 + o;       o += (size_t)N_IP * D;
  u16* P1 = w16 + o;         o += (size_t)N_IP * D;
  u16* P2 = w16 + o;         o += (size_t)N_CONN * D;
  u16* gikb = w16 + o;       o += 49152;
  u16* girb = w16 + o;       o += 49152;
  u16* gckb = w16 + o;       o += 49152;
  u16* gcrb = w16 + o;       o += 49152;
  u16* wm1b = w16 + o;       o += 16384;
  u16* wm2b = w16 + o;       o += 16384;
  u16* wm1t = w16 + o;       o += 16384;
  u16* wm2t = w16 + o;       o += 16384;
  u16* wr1b = w16 + o;       o += 16384;
  u16* wr2b = w16 + o;       o += 8192;
  int* ip = (int*)(w16 + o);
  int* cnt1 = ip;  ip += N_CONN;
  int* cnt2 = ip;  ip += N_IP;
  int* off1 = ip;  ip += N_CONN;
  int* off2 = ip;  ip += N_IP;
  int* cur1 = ip;  ip += N_CONN;
  int* cur2 = ip;  ip += N_IP;
  int* srcs1 = ip; ip += NE;
  int* srcs2 = ip; ip += NE;
  int* bsum1 = ip; ip += 256;
  int* bsum2 = ip; ip += 256;

  const int BT = 256;

  // ---- fused init + weight prep ----
  const int nstate = (N_IP + N_CONN) * D;
  k_init_all<<<(nstate + BT - 1) / BT, BT, 0, stream>>>(ip_state, conn_state, feat, cnt1);
  k_prep_all<<<(286720 + BT - 1) / BT, BT, 0, stream>>>(
      gik, gir, gck, gcr, Wm1, Wm2, Wr1, Wr2,
      gikb, girb, gckb, gcrb, wm1b, wm2b, wm1t, wm2t, wr1b, wr2b);

  // ---- build CSR ----
  k_count<<<(NE + BT - 1) / BT, BT, 0, stream>>>(dst1, dst2, cnt1, cnt2);
  const int nb1 = (N_CONN + 1023) / 1024, nb2 = (N_IP + 1023) / 1024;
  k_scan_part2<<<nb1 + nb2, 256, 0, stream>>>(cnt1, bsum1, N_CONN, nb1, cnt2, bsum2, N_IP);
  k_scan_mid2<<<1, 256, 0, stream>>>(bsum1, nb1, bsum2, nb2);
  k_scan_final2<<<nb1 + nb2, 256, 0, stream>>>(cnt1, bsum1, off1, N_CONN, nb1,
                                               cnt2, bsum2, off2, N_IP);
  k_copyint<<<(N_CONN + N_IP + BT - 1) / BT, BT, 0, stream>>>(off1, cur1, N_CONN + N_IP);
  k_scatter<<<(NE + BT - 1) / BT, BT, 0, stream>>>(src1, dst1, src2, dst2,
                                                   cur1, cur2, srcs1, srcs2);

  const int t64ip = (N_IP + 63) / 64;       // 313
  const int t64cn = (N_CONN + 63) / 64;     // 1563
  const int t128ip = (N_IP + 127) / 128;    // 157
  const int t128cn = (N_CONN + 127) / 128;  // 782

  for (int t = 0; t < T_ROUNDS; t++) {
    k_gemmP<<<t64ip + t64cn, 256, 0, stream>>>(ip_state, wm1t, P1, N_IP, t64ip,
                                               conn_state, wm2t, P2, N_CONN);
    k_qgather<<<t64cn + t64ip, 256, 0, stream>>>(
        conn_state, wm1b, bm1, P1, srcs1, off1, cnt1, sum1, N_CONN, t64cn,
        ip_state, wm2b, bm2, P2, srcs2, off2, cnt2, sum2, N_IP);
    k_gru_fused<<<t128cn + t128ip, 256, 0, stream>>>(
        sum1, gckb, gcrb, gcb, conn_state, N_CONN, t128cn,
        sum2, gikb, girb, gib, ip_state, N_IP);
  }

  k_readout2<<<t64cn, 256, 0, stream>>>(conn_state, wr1b, br1, wr2b, br2,
                                        Wr3, br3, out, N_CONN);
}

// Round 9
// 555.669 us; speedup vs baseline: 1.2062x; 1.2062x over previous
//
#include <hip/hip_runtime.h>
#include <math.h>

#define D 128
#define NF 10
#define N_IP 20000
#define N_CONN 100000
#define NE 200000
#define T_ROUNDS 3

typedef unsigned short u16;
using bf16x8 = __attribute__((ext_vector_type(8))) short;
using floatx4 = __attribute__((ext_vector_type(4))) float;

__device__ inline u16 f2bf(float f) {
  union { float f; unsigned u; } v; v.f = f;
  unsigned u = v.u;
  return (u16)((u + 0x7fffu + ((u >> 16) & 1u)) >> 16);  // RNE
}
__device__ inline float bf2f(u16 h) {
  union { unsigned u; float f; } v; v.u = ((unsigned)h) << 16; return v.f;
}

__device__ inline float fsigmoid(float s) { return 1.f / (1.f + __expf(-s)); }
__device__ inline float ftanh(float a) {
  a = fminf(fmaxf(a, -15.f), 15.f);
  float e = __expf(2.f * a);
  return (e - 1.f) / (e + 1.f);
}

// ---------------- fused init: states + cnt zero ----------------
__global__ void k_init_all(u16* __restrict__ ip_state, u16* __restrict__ conn_state,
                           const float* __restrict__ feat, int* __restrict__ cnt) {
  int i = blockIdx.x * blockDim.x + threadIdx.x;
  const int nip = N_IP * D;
  const int nstate = (N_IP + N_CONN) * D;
  if (i < nip) {
    ip_state[i] = 0x3F80;  // bf16(1.0)
  } else if (i < nstate) {
    int j = i - nip;
    int r = j >> 7, c = j & 127;
    conn_state[j] = (c < NF) ? f2bf(feat[r * NF + c]) : (u16)0;
  }
  if (i < N_CONN + N_IP) cnt[i] = 0;
}

// ---------------- fused weight prep (all matrices, bf16 [col][k]) ----------------
__global__ void k_prep_all(
    const float* __restrict__ gik, const float* __restrict__ gir,
    const float* __restrict__ gck, const float* __restrict__ gcr,
    const float* __restrict__ Wm1, const float* __restrict__ Wm2,
    const float* __restrict__ Wr1, const float* __restrict__ Wr2,
    u16* __restrict__ gikb, u16* __restrict__ girb,
    u16* __restrict__ gckb, u16* __restrict__ gcrb,
    u16* __restrict__ wm1b, u16* __restrict__ wm2b,
    u16* __restrict__ wm1t, u16* __restrict__ wm2t,
    u16* __restrict__ wr1b, u16* __restrict__ wr2b) {
  int i = blockIdx.x * blockDim.x + threadIdx.x;
  if (i < 196608) {  // 4 GRU mats (128x384 -> [col][k] 384x128)
    int m = i / 49152, r = i % 49152;
    const float* W = (m == 0) ? gik : (m == 1) ? gir : (m == 2) ? gck : gcr;
    u16* Wb = (m == 0) ? gikb : (m == 1) ? girb : (m == 2) ? gckb : gcrb;
    int col = r >> 7, k = r & 127;
    Wb[r] = f2bf(W[k * 384 + col]);
  } else if (i < 278528) {  // 5 x 128x128 blocks
    int j = i - 196608;
    int m = j / 16384, r = j % 16384;
    const float* W; u16* Wb; int k0;
    if (m == 0) { W = Wm1; Wb = wm1b; k0 = 128; }
    else if (m == 1) { W = Wm2; Wb = wm2b; k0 = 128; }
    else if (m == 2) { W = Wm1; Wb = wm1t; k0 = 0; }
    else if (m == 3) { W = Wm2; Wb = wm2t; k0 = 0; }
    else { W = Wr1; Wb = wr1b; k0 = 0; }
    int col = r >> 7, k = r & 127;
    Wb[r] = f2bf(W[(k0 + k) * 128 + col]);
  } else if (i < 286720) {  // Wr2 128x64 -> [col][k] 64x128
    int r = i - 278528;
    int col = r >> 7, k = r & 127;
    wr2b[r] = f2bf(Wr2[k * 64 + col]);
  }
}

__global__ void k_count(const int* __restrict__ d1, const int* __restrict__ d2,
                        int* __restrict__ c1, int* __restrict__ c2) {
  int e = blockIdx.x * blockDim.x + threadIdx.x;
  if (e >= NE) return;
  atomicAdd(&c1[d1[e]], 1);
  atomicAdd(&c2[d2[e]], 1);
}

// ---------------- merged 3-pass exclusive scan (both segment arrays) ----------------
__global__ void k_scan_part2(const int* __restrict__ cnt1, int* __restrict__ bsum1,
                             int n1, int nb1,
                             const int* __restrict__ cnt2, int* __restrict__ bsum2, int n2) {
  const int* cnt; int* bsum; int n, b;
  if ((int)blockIdx.x < nb1) { cnt = cnt1; bsum = bsum1; n = n1; b = blockIdx.x; }
  else { cnt = cnt2; bsum = bsum2; n = n2; b = blockIdx.x - nb1; }
  int t = threadIdx.x;
  int base = b * 1024 + t * 4;
  int s = 0;
#pragma unroll
  for (int i = 0; i < 4; i++) { int j = base + i; if (j < n) s += cnt[j]; }
  for (int d = 32; d > 0; d >>= 1) s += __shfl_xor(s, d, 64);
  __shared__ int wred[4];
  int lane = t & 63, wv = t >> 6;
  if (lane == 0) wred[wv] = s;
  __syncthreads();
  if (t == 0) bsum[b] = wred[0] + wred[1] + wred[2] + wred[3];
}

__device__ inline void scan_mid_body(int* bsum, int m, int t) {
  int v = (t < m) ? bsum[t] : 0;
  int lane = t & 63, wv = t >> 6;
  int x = v;
  for (int d = 1; d < 64; d <<= 1) { int y = __shfl_up(x, d, 64); if (lane >= d) x += y; }
  __shared__ int wsum[4];
  if (lane == 63) wsum[wv] = x;
  __syncthreads();
  int add = 0;
  for (int i = 0; i < wv; i++) add += wsum[i];
  int ex = add + x - v;
  if (t < m) bsum[t] = ex;
  __syncthreads();
}

__global__ void k_scan_mid2(int* __restrict__ bsum1, int m1, int* __restrict__ bsum2, int m2) {
  int t = threadIdx.x;
  scan_mid_body(bsum1, m1, t);
  scan_mid_body(bsum2, m2, t);
}

__global__ void k_scan_final2(const int* __restrict__ cnt1, const int* __restrict__ bsum1,
                              int* __restrict__ off1, int n1, int nb1,
                              const int* __restrict__ cnt2, const int* __restrict__ bsum2,
                              int* __restrict__ off2, int n2) {
  const int* cnt; const int* bsum; int* off; int n, b;
  if ((int)blockIdx.x < nb1) { cnt = cnt1; bsum = bsum1; off = off1; n = n1; b = blockIdx.x; }
  else { cnt = cnt2; bsum = bsum2; off = off2; n = n2; b = blockIdx.x - nb1; }
  int t = threadIdx.x;
  int base = b * 1024 + t * 4;
  int vals[4]; int s = 0;
#pragma unroll
  for (int i = 0; i < 4; i++) {
    int j = base + i;
    vals[i] = (j < n) ? cnt[j] : 0;
    s += vals[i];
  }
  int lane = t & 63, wv = t >> 6;
  int x = s;
  for (int d = 1; d < 64; d <<= 1) { int y = __shfl_up(x, d, 64); if (lane >= d) x += y; }
  __shared__ int wsum[4];
  if (lane == 63) wsum[wv] = x;
  __syncthreads();
  int add = 0;
  for (int i = 0; i < wv; i++) add += wsum[i];
  int run = add + x - s + bsum[b];
#pragma unroll
  for (int i = 0; i < 4; i++) {
    int j = base + i;
    if (j < n) off[j] = run;
    run += vals[i];
  }
}

__global__ void k_copyint(const int* __restrict__ a, int* __restrict__ b, int n) {
  int i = blockIdx.x * blockDim.x + threadIdx.x;
  if (i < n) b[i] = a[i];
}

__global__ void k_scatter(const int* __restrict__ s1, const int* __restrict__ d1,
                          const int* __restrict__ s2, const int* __restrict__ d2,
                          int* __restrict__ cur1, int* __restrict__ cur2,
                          int* __restrict__ o1, int* __restrict__ o2) {
  int e = blockIdx.x * blockDim.x + threadIdx.x;
  if (e >= NE) return;
  int p1 = atomicAdd(&cur1[d1[e]], 1);
  o1[p1] = s1[e];
  int p2 = atomicAdd(&cur2[d2[e]], 1);
  o2[p2] = s2[e];
}

// ---------------- merged P-GEMM (bf16 in/out): P = S @ Wt^T ----------------
__global__ __launch_bounds__(256) void k_gemmP(
    const u16* __restrict__ S1, const u16* __restrict__ Wt1, u16* __restrict__ P1,
    int M1, int tiles1,
    const u16* __restrict__ S2, const u16* __restrict__ Wt2, u16* __restrict__ P2,
    int M2) {
  __shared__ __align__(16) u16 Wls[128 * 128];  // 32KB; reused as C (64x136)
  const u16* S; const u16* Wt; u16* P; int M, bm;
  if ((int)blockIdx.x < tiles1) { S = S1; Wt = Wt1; P = P1; M = M1; bm = blockIdx.x * 64; }
  else { S = S2; Wt = Wt2; P = P2; M = M2; bm = (blockIdx.x - tiles1) * 64; }
  const int tid = threadIdx.x, wv = tid >> 6, lane = tid & 63;
  const int lrow = lane & 15, quad = lane >> 4;
#pragma unroll
  for (int i = 0; i < 8; i++) {  // stage W swizzled
    int task = i * 256 + tid;
    int col = task >> 4, gr = task & 15;
    uint4 v = *(const uint4*)(Wt + (size_t)col * 128 + gr * 8);
    *(uint4*)(Wls + (size_t)col * 128 + ((gr ^ (col & 15)) * 8)) = v;
  }
  const int arow = bm + wv * 16 + lrow;
  const bool arv = arow < M;
  const bf16x8 zv = {0, 0, 0, 0, 0, 0, 0, 0};
  bf16x8 a[4];
#pragma unroll
  for (int ks = 0; ks < 4; ks++)
    a[ks] = arv ? *(const bf16x8*)(S + (size_t)arow * 128 + quad * 8 + ks * 32) : zv;
  __syncthreads();
  floatx4 acc[8];
#pragma unroll
  for (int ct = 0; ct < 8; ct++) acc[ct] = {0.f, 0.f, 0.f, 0.f};
#pragma unroll
  for (int ks = 0; ks < 4; ks++) {
#pragma unroll
    for (int ct = 0; ct < 8; ct++) {
      int col = ct * 16 + lrow;
      bf16x8 b = *(const bf16x8*)(Wls + (size_t)col * 128 + (((4 * ks + quad) ^ lrow) * 8));
      acc[ct] = __builtin_amdgcn_mfma_f32_16x16x32_bf16(a[ks], b, acc[ct], 0, 0, 0);
    }
  }
  __syncthreads();  // W reads done; reuse as C
  u16* Cls = Wls;   // 64 x 136
#pragma unroll
  for (int ct = 0; ct < 8; ct++) {
    int col = ct * 16 + lrow;
#pragma unroll
    for (int reg = 0; reg < 4; reg++) {
      int lr = wv * 16 + quad * 4 + reg;
      Cls[(size_t)lr * 136 + col] = f2bf(acc[ct][reg]);
    }
  }
  __syncthreads();
#pragma unroll
  for (int i = 0; i < 4; i++) {  // coalesced bf16 write-out
    int task = i * 256 + tid;
    int row = task >> 4, c8 = task & 15;
    int gr2 = bm + row;
    if (gr2 < M)
      *(uint4*)(P + (size_t)gr2 * 128 + c8 * 8) = *(const uint4*)(Cls + (size_t)row * 136 + c8 * 8);
  }
}

// ---------------- merged fused Q-GEMM + gather-mean (bf16 in/out) ----------------
__global__ __launch_bounds__(256) void k_qgather(
    const u16* __restrict__ S1, const u16* __restrict__ Wb1, const float* __restrict__ bias1,
    const u16* __restrict__ P1g, const int* __restrict__ srcs1g,
    const int* __restrict__ off1g, const int* __restrict__ cnt1g,
    u16* __restrict__ out1, int n1, int tiles1,
    const u16* __restrict__ S2, const u16* __restrict__ Wb2, const float* __restrict__ bias2,
    const u16* __restrict__ P2g, const int* __restrict__ srcs2g,
    const int* __restrict__ off2g, const int* __restrict__ cnt2g,
    u16* __restrict__ out2, int n2) {
  __shared__ __align__(16) char smem[64 * 132 * 4];  // 33792 B
  u16* Wls = (u16*)smem;
  float* Qls = (float*)smem;
  const u16* S; const u16* Wb; const float* bias; const u16* P;
  const int* srcs; const int* off; const int* cnt; u16* outm; int nnodes, bm;
  if ((int)blockIdx.x < tiles1) {
    S = S1; Wb = Wb1; bias = bias1; P = P1g; srcs = srcs1g; off = off1g; cnt = cnt1g;
    outm = out1; nnodes = n1; bm = blockIdx.x * 64;
  } else {
    S = S2; Wb = Wb2; bias = bias2; P = P2g; srcs = srcs2g; off = off2g; cnt = cnt2g;
    outm = out2; nnodes = n2; bm = (blockIdx.x - tiles1) * 64;
  }
  const int tid = threadIdx.x, wv = tid >> 6, lane = tid & 63;
  const int lrow = lane & 15, quad = lane >> 4;
#pragma unroll
  for (int i = 0; i < 8; i++) {  // stage W swizzled
    int task = i * 256 + tid;
    int col = task >> 4, gr = task & 15;
    uint4 v = *(const uint4*)(Wb + (size_t)col * 128 + gr * 8);
    *(uint4*)(Wls + (size_t)col * 128 + ((gr ^ (col & 15)) * 8)) = v;
  }
  const int arow = bm + wv * 16 + lrow;
  const bool arv = arow < nnodes;
  const bf16x8 zv = {0, 0, 0, 0, 0, 0, 0, 0};
  bf16x8 a[4];
#pragma unroll
  for (int ks = 0; ks < 4; ks++)
    a[ks] = arv ? *(const bf16x8*)(S + (size_t)arow * 128 + quad * 8 + ks * 32) : zv;
  __syncthreads();
  floatx4 acc[8];
#pragma unroll
  for (int ct = 0; ct < 8; ct++) acc[ct] = {0.f, 0.f, 0.f, 0.f};
#pragma unroll
  for (int ks = 0; ks < 4; ks++) {
#pragma unroll
    for (int ct = 0; ct < 8; ct++) {
      int col = ct * 16 + lrow;
      bf16x8 b = *(const bf16x8*)(Wls + (size_t)col * 128 + (((4 * ks + quad) ^ lrow) * 8));
      acc[ct] = __builtin_amdgcn_mfma_f32_16x16x32_bf16(a[ks], b, acc[ct], 0, 0, 0);
    }
  }
  __syncthreads();  // W reads done; reuse smem as Q (fp32, stride 132)
#pragma unroll
  for (int ct = 0; ct < 8; ct++) {
    int col = ct * 16 + lrow;
    float bv = bias[col];
#pragma unroll
    for (int reg = 0; reg < 4; reg++) {
      int lr = wv * 16 + quad * 4 + reg;
      Qls[(size_t)lr * 132 + col] = acc[ct][reg] + bv;
    }
  }
  __syncthreads();
  // gather: 64 nodes x 16 col-granules (8 bf16 each) = 1024 tasks
#pragma unroll
  for (int it = 0; it < 4; it++) {
    int task = it * 256 + tid;
    int nl = task >> 4, c8 = (task & 15) << 3;
    int node = bm + nl;
    if (node >= nnodes) continue;
    const float* qp = Qls + (size_t)nl * 132 + c8;
    float4 qa = *(const float4*)(qp);
    float4 qb = *(const float4*)(qp + 4);
    float q[8] = {qa.x, qa.y, qa.z, qa.w, qb.x, qb.y, qb.z, qb.w};
    float acg[8] = {0.f, 0.f, 0.f, 0.f, 0.f, 0.f, 0.f, 0.f};
    int o = off[node], n = cnt[node];
    int i = 0;
    for (; i + 4 <= n; i += 4) {
      int s0 = srcs[o + i], s1 = srcs[o + i + 1], s2 = srcs[o + i + 2], s3 = srcs[o + i + 3];
      uint4 v0 = *(const uint4*)(P + (size_t)s0 * 128 + c8);
      uint4 v1 = *(const uint4*)(P + (size_t)s1 * 128 + c8);
      uint4 v2 = *(const uint4*)(P + (size_t)s2 * 128 + c8);
      uint4 v3 = *(const uint4*)(P + (size_t)s3 * 128 + c8);
      unsigned w[16] = {v0.x, v0.y, v0.z, v0.w, v1.x, v1.y, v1.z, v1.w,
                        v2.x, v2.y, v2.z, v2.w, v3.x, v3.y, v3.z, v3.w};
#pragma unroll
      for (int e = 0; e < 4; e++)
#pragma unroll
        for (int k = 0; k < 4; k++) {
          unsigned ww = w[e * 4 + k];
          float lo = __uint_as_float(ww << 16);
          float hi = __uint_as_float(ww & 0xffff0000u);
          acg[2 * k] += fmaxf(lo + q[2 * k], 0.f);
          acg[2 * k + 1] += fmaxf(hi + q[2 * k + 1], 0.f);
        }
    }
    for (; i < n; i++) {
      int s0 = srcs[o + i];
      uint4 v0 = *(const uint4*)(P + (size_t)s0 * 128 + c8);
      unsigned w[4] = {v0.x, v0.y, v0.z, v0.w};
#pragma unroll
      for (int k = 0; k < 4; k++) {
        unsigned ww = w[k];
        float lo = __uint_as_float(ww << 16);
        float hi = __uint_as_float(ww & 0xffff0000u);
        acg[2 * k] += fmaxf(lo + q[2 * k], 0.f);
        acg[2 * k + 1] += fmaxf(hi + q[2 * k + 1], 0.f);
      }
    }
    float inv = 1.f / fmaxf((float)n, 1.f);
    bf16x8 ov;
#pragma unroll
    for (int k = 0; k < 8; k++) ov[k] = (short)f2bf(acg[k] * inv);
    *(bf16x8*)(outm + (size_t)node * 128 + c8) = ov;
  }
}

// ---------------- merged fused GRU v6: 128 rows/block, 16-col chunks, 3 blocks/CU ----------------
// LDS 24.6KB (6 blocks fit); __launch_bounds__(256,3) -> VGPR cap ~170 vs ~150 needed
// (NOT 4: that caps at 64 VGPR and spills -- round-8 regression, FETCH 221MB).
__global__ __launch_bounds__(256, 3) void k_gru_fused(
    const u16* __restrict__ X1, const u16* __restrict__ Wx1, const u16* __restrict__ Wh1,
    const float* __restrict__ b1, u16* __restrict__ H1, int r1, int tiles1,
    const u16* __restrict__ X2, const u16* __restrict__ Wx2, const u16* __restrict__ Wh2,
    const float* __restrict__ b2, u16* __restrict__ H2, int r2) {
  __shared__ __align__(16) u16 Ls[6 * 16 * 128];  // 24576 B
  const u16* X; const u16* Wxb; const u16* Whb; const float* bias; u16* H;
  int rows, bm;
  if ((int)blockIdx.x < tiles1) {
    X = X1; Wxb = Wx1; Whb = Wh1; bias = b1; H = H1; rows = r1; bm = blockIdx.x * 128;
  } else {
    X = X2; Wxb = Wx2; Whb = Wh2; bias = b2; H = H2; rows = r2;
    bm = (blockIdx.x - tiles1) * 128;
  }
  const int tid = threadIdx.x, wv = tid >> 6, lane = tid & 63;
  const int lrow = lane & 15, quad = lane >> 4;
  const bf16x8 zv = {0, 0, 0, 0, 0, 0, 0, 0};
  bf16x8 ax[2][4], ah[2][4];  // 64 VGPRs, live across all chunks
#pragma unroll
  for (int tile = 0; tile < 2; tile++) {
    int arow = bm + tile * 64 + wv * 16 + lrow;
    bool arv = arow < rows;
    const u16* xp = X + (size_t)arow * 128 + quad * 8;
    const u16* hp = H + (size_t)arow * 128 + quad * 8;
#pragma unroll
    for (int ks = 0; ks < 4; ks++) {
      ax[tile][ks] = arv ? *(const bf16x8*)(xp + ks * 32) : zv;
      ah[tile][ks] = arv ? *(const bf16x8*)(hp + ks * 32) : zv;
    }
  }
  for (int ch = 0; ch < 8; ch++) {
    __syncthreads();  // prev chunk's LDS readers done
    // stage: 1536 uint4 tasks in 2 passes of 3/thread (12 staging VGPRs)
#pragma unroll
    for (int p = 0; p < 2; p++) {
      uint4 v[3];
#pragma unroll
      for (int j = 0; j < 3; j++) {
        int task = (p * 3 + j) * 256 + tid;
        int seg = task >> 8, rem = task & 255;
        int col = rem >> 4, gr = rem & 15;
        const u16* gsrc = (seg < 3 ? Wxb : Whb) +
                          (size_t)((seg < 3 ? seg : seg - 3) * 128 + ch * 16 + col) * 128 + gr * 8;
        v[j] = *(const uint4*)gsrc;
      }
#pragma unroll
      for (int j = 0; j < 3; j++) {
        int task = (p * 3 + j) * 256 + tid;
        int seg = task >> 8, rem = task & 255;
        int col = rem >> 4, gr = rem & 15;
        *(uint4*)(Ls + (size_t)(seg * 16 + col) * 128 + ((gr ^ col) * 8)) = v[j];
      }
    }
    __syncthreads();
    floatx4 acc[2][3][2];  // tile, gate, x/h -> 48 VGPRs
#pragma unroll
    for (int tile = 0; tile < 2; tile++)
#pragma unroll
      for (int g = 0; g < 3; g++) {
        acc[tile][g][0] = {0.f, 0.f, 0.f, 0.f};
        acc[tile][g][1] = {0.f, 0.f, 0.f, 0.f};
      }
#pragma unroll
    for (int ks = 0; ks < 4; ks++) {
      int posu = ((4 * ks + quad) ^ lrow) * 8;
#pragma unroll
      for (int g = 0; g < 3; g++) {
        bf16x8 bx = *(const bf16x8*)(Ls + (size_t)(g * 16 + lrow) * 128 + posu);
        bf16x8 bh = *(const bf16x8*)(Ls + (size_t)((3 + g) * 16 + lrow) * 128 + posu);
        acc[0][g][0] = __builtin_amdgcn_mfma_f32_16x16x32_bf16(ax[0][ks], bx, acc[0][g][0], 0, 0, 0);
        acc[0][g][1] = __builtin_amdgcn_mfma_f32_16x16x32_bf16(ah[0][ks], bh, acc[0][g][1], 0, 0, 0);
        acc[1][g][0] = __builtin_amdgcn_mfma_f32_16x16x32_bf16(ax[1][ks], bx, acc[1][g][0], 0, 0, 0);
        acc[1][g][1] = __builtin_amdgcn_mfma_f32_16x16x32_bf16(ah[1][ks], bh, acc[1][g][1], 0, 0, 0);
      }
    }
    int hcol = ch * 16 + lrow;
    float bxz = bias[hcol];
    float bxr = bias[128 + hcol];
    float bxh = bias[256 + hcol];
    float bhz = bias[384 + hcol];
    float bhr = bias[384 + 128 + hcol];
    float bhh = bias[384 + 256 + hcol];
#pragma unroll
    for (int tile = 0; tile < 2; tile++) {
#pragma unroll
      for (int reg = 0; reg < 4; reg++) {
        int r = bm + tile * 64 + wv * 16 + quad * 4 + reg;
        if (r < rows) {
          float xz = acc[tile][0][0][reg] + bxz;
          float xr = acc[tile][1][0][reg] + bxr;
          float xh = acc[tile][2][0][reg] + bxh;
          float hz = acc[tile][0][1][reg] + bhz;
          float hr = acc[tile][1][1][reg] + bhr;
          float hh = acc[tile][2][1][reg] + bhh;
          float z = fsigmoid(xz + hz);
          float rr = fsigmoid(xr + hr);
          float hc = ftanh(xh + rr * hh);
          u16* hp2 = H + (size_t)r * 128 + hcol;
          float hold = bf2f(*hp2);
          *hp2 = f2bf(z * hold + (1.f - z) * hc);
        }
      }
    }
  }
}

// ---------------- fully fused readout: 2 GEMMs + logits + softmax ----------------
__global__ __launch_bounds__(256) void k_readout2(
    const u16* __restrict__ S, const u16* __restrict__ W1b, const float* __restrict__ b1,
    const u16* __restrict__ W2b, const float* __restrict__ b2,
    const float* __restrict__ W3, const float* __restrict__ b3,
    float* __restrict__ out, int M) {
  __shared__ __align__(16) char smem[64 * 132 * 4];  // 33792 B
  u16* Wls = (u16*)smem;                 // phase1: W1 32KB swizzled
  u16* H1ls = (u16*)smem;                // phase2/3: 64 x 136 u16
  u16* W2ls = (u16*)(smem + 17408);      // 64 x 128 u16
  u16* H2ls = (u16*)smem;                // phase4/5: 64 x 72 u16
  float* W3ls = (float*)(smem + 9216);
  float* b3ls = (float*)(smem + 9216 + 3840);
  const int tid = threadIdx.x, wv = tid >> 6, lane = tid & 63;
  const int lrow = lane & 15, quad = lane >> 4;
  const int bm = blockIdx.x * 64;
#pragma unroll
  for (int i = 0; i < 8; i++) {
    int task = i * 256 + tid;
    int col = task >> 4, gr = task & 15;
    uint4 v = *(const uint4*)(W1b + (size_t)col * 128 + gr * 8);
    *(uint4*)(Wls + (size_t)col * 128 + ((gr ^ (col & 15)) * 8)) = v;
  }
  const int arow = bm + wv * 16 + lrow;
  const bool arv = arow < M;
  const bf16x8 zv = {0, 0, 0, 0, 0, 0, 0, 0};
  bf16x8 a[4];
#pragma unroll
  for (int ks = 0; ks < 4; ks++)
    a[ks] = arv ? *(const bf16x8*)(S + (size_t)arow * 128 + quad * 8 + ks * 32) : zv;
  __syncthreads();
  floatx4 acc1[8];
#pragma unroll
  for (int ct = 0; ct < 8; ct++) acc1[ct] = {0.f, 0.f, 0.f, 0.f};
#pragma unroll
  for (int ks = 0; ks < 4; ks++) {
#pragma unroll
    for (int ct = 0; ct < 8; ct++) {
      int col = ct * 16 + lrow;
      bf16x8 b = *(const bf16x8*)(Wls + (size_t)col * 128 + (((4 * ks + quad) ^ lrow) * 8));
      acc1[ct] = __builtin_amdgcn_mfma_f32_16x16x32_bf16(a[ks], b, acc1[ct], 0, 0, 0);
    }
  }
  __syncthreads();
#pragma unroll
  for (int ct = 0; ct < 8; ct++) {
    int col = ct * 16 + lrow;
    float bv = b1[col];
#pragma unroll
    for (int reg = 0; reg < 4; reg++) {
      int lr = wv * 16 + quad * 4 + reg;
      H1ls[(size_t)lr * 136 + col] = f2bf(fmaxf(acc1[ct][reg] + bv, 0.f));
    }
  }
#pragma unroll
  for (int i = 0; i < 4; i++) {
    int task = i * 256 + tid;
    int col = task >> 4, gr = task & 15;
    uint4 v = *(const uint4*)(W2b + (size_t)col * 128 + gr * 8);
    *(uint4*)(W2ls + (size_t)col * 128 + ((gr ^ (col & 15)) * 8)) = v;
  }
  __syncthreads();
  bf16x8 a2[4];
#pragma unroll
  for (int ks = 0; ks < 4; ks++)
    a2[ks] = *(const bf16x8*)(H1ls + (size_t)(wv * 16 + lrow) * 136 + quad * 8 + ks * 32);
  floatx4 acc2[4];
#pragma unroll
  for (int ct = 0; ct < 4; ct++) acc2[ct] = {0.f, 0.f, 0.f, 0.f};
#pragma unroll
  for (int ks = 0; ks < 4; ks++) {
#pragma unroll
    for (int ct = 0; ct < 4; ct++) {
      int col = ct * 16 + lrow;
      bf16x8 b = *(const bf16x8*)(W2ls + (size_t)col * 128 + (((4 * ks + quad) ^ lrow) * 8));
      acc2[ct] = __builtin_amdgcn_mfma_f32_16x16x32_bf16(a2[ks], b, acc2[ct], 0, 0, 0);
    }
  }
  __syncthreads();
#pragma unroll
  for (int ct = 0; ct < 4; ct++) {
    int col = ct * 16 + lrow;
    float bv = b2[col];
#pragma unroll
    for (int reg = 0; reg < 4; reg++) {
      int lr = wv * 16 + quad * 4 + reg;
      H2ls[(size_t)lr * 72 + col] = f2bf(fmaxf(acc2[ct][reg] + bv, 0.f));
    }
  }
  for (int l = tid; l < 960; l += 256) W3ls[l] = W3[l];
  if (tid < 15) b3ls[tid] = b3[tid];
  __syncthreads();
  if (tid < 64) {
    int row = tid, gr2 = bm + row;
    if (gr2 < M) {
      float lg[15];
#pragma unroll
      for (int c = 0; c < 15; c++) lg[c] = b3ls[c];
      for (int k = 0; k < 64; k++) {
        float hk = bf2f(H2ls[(size_t)row * 72 + k]);
#pragma unroll
        for (int c = 0; c < 15; c++) lg[c] += hk * W3ls[k * 15 + c];
      }
      float m = lg[0];
#pragma unroll
      for (int c = 1; c < 15; c++) m = fmaxf(m, lg[c]);
      float ssum = 0.f;
#pragma unroll
      for (int c = 0; c < 15; c++) { lg[c] = __expf(lg[c] - m); ssum += lg[c]; }
      float inv = 1.f / ssum;
#pragma unroll
      for (int c = 0; c < 15; c++) out[(size_t)gr2 * 15 + c] = lg[c] * inv;
    }
  }
}

// ---------------- launch ----------------
extern "C" void kernel_launch(void* const* d_in, const int* in_sizes, int n_in,
                              void* d_out, int out_size, void* d_ws, size_t ws_size,
                              hipStream_t stream) {
  const float* feat = (const float*)d_in[0];
  const int* src1 = (const int*)d_in[1];
  const int* dst1 = (const int*)d_in[2];
  const int* src2 = (const int*)d_in[3];
  const int* dst2 = (const int*)d_in[4];
  const float* Wm1 = (const float*)d_in[5];
  const float* bm1 = (const float*)d_in[6];
  const float* Wm2 = (const float*)d_in[7];
  const float* bm2 = (const float*)d_in[8];
  const float* gik = (const float*)d_in[9];
  const float* gir = (const float*)d_in[10];
  const float* gib = (const float*)d_in[11];
  const float* gck = (const float*)d_in[12];
  const float* gcr = (const float*)d_in[13];
  const float* gcb = (const float*)d_in[14];
  const float* Wr1 = (const float*)d_in[15];
  const float* br1 = (const float*)d_in[16];
  const float* Wr2 = (const float*)d_in[17];
  const float* br2 = (const float*)d_in[18];
  const float* Wr3 = (const float*)d_in[19];
  const float* br3 = (const float*)d_in[20];
  float* out = (float*)d_out;

  // ---- workspace layout (u16 units) ----
  u16* w16 = (u16*)d_ws;
  size_t o = 0;
  u16* ip_state = w16 + o;   o += (size_t)N_IP * D;
  u16* conn_state = w16 + o; o += (size_t)N_CONN * D;
  u16* sum1 = w16 + o;       o += (size_t)N_CONN * D;
  u16* sum2 = w16 + o;       o += (size_t)N_IP * D;
  u16* P1 = w16 + o;         o += (size_t)N_IP * D;
  u16* P2 = w16 + o;         o += (size_t)N_CONN * D;
  u16* gikb = w16 + o;       o += 49152;
  u16* girb = w16 + o;       o += 49152;
  u16* gckb = w16 + o;       o += 49152;
  u16* gcrb = w16 + o;       o += 49152;
  u16* wm1b = w16 + o;       o += 16384;
  u16* wm2b = w16 + o;       o += 16384;
  u16* wm1t = w16 + o;       o += 16384;
  u16* wm2t = w16 + o;       o += 16384;
  u16* wr1b = w16 + o;       o += 16384;
  u16* wr2b = w16 + o;       o += 8192;
  int* ip = (int*)(w16 + o);
  int* cnt1 = ip;  ip += N_CONN;
  int* cnt2 = ip;  ip += N_IP;
  int* off1 = ip;  ip += N_CONN;
  int* off2 = ip;  ip += N_IP;
  int* cur1 = ip;  ip += N_CONN;
  int* cur2 = ip;  ip += N_IP;
  int* srcs1 = ip; ip += NE;
  int* srcs2 = ip; ip += NE;
  int* bsum1 = ip; ip += 256;
  int* bsum2 = ip; ip += 256;

  const int BT = 256;

  // ---- fused init + weight prep ----
  const int nstate = (N_IP + N_CONN) * D;
  k_init_all<<<(nstate + BT - 1) / BT, BT, 0, stream>>>(ip_state, conn_state, feat, cnt1);
  k_prep_all<<<(286720 + BT - 1) / BT, BT, 0, stream>>>(
      gik, gir, gck, gcr, Wm1, Wm2, Wr1, Wr2,
      gikb, girb, gckb, gcrb, wm1b, wm2b, wm1t, wm2t, wr1b, wr2b);

  // ---- build CSR ----
  k_count<<<(NE + BT - 1) / BT, BT, 0, stream>>>(dst1, dst2, cnt1, cnt2);
  const int nb1 = (N_CONN + 1023) / 1024, nb2 = (N_IP + 1023) / 1024;
  k_scan_part2<<<nb1 + nb2, 256, 0, stream>>>(cnt1, bsum1, N_CONN, nb1, cnt2, bsum2, N_IP);
  k_scan_mid2<<<1, 256, 0, stream>>>(bsum1, nb1, bsum2, nb2);
  k_scan_final2<<<nb1 + nb2, 256, 0, stream>>>(cnt1, bsum1, off1, N_CONN, nb1,
                                               cnt2, bsum2, off2, N_IP);
  k_copyint<<<(N_CONN + N_IP + BT - 1) / BT, BT, 0, stream>>>(off1, cur1, N_CONN + N_IP);
  k_scatter<<<(NE + BT - 1) / BT, BT, 0, stream>>>(src1, dst1, src2, dst2,
                                                   cur1, cur2, srcs1, srcs2);

  const int t64ip = (N_IP + 63) / 64;       // 313
  const int t64cn = (N_CONN + 63) / 64;     // 1563
  const int t128ip = (N_IP + 127) / 128;    // 157
  const int t128cn = (N_CONN + 127) / 128;  // 782

  for (int t = 0; t < T_ROUNDS; t++) {
    k_gemmP<<<t64ip + t64cn, 256, 0, stream>>>(ip_state, wm1t, P1, N_IP, t64ip,
                                               conn_state, wm2t, P2, N_CONN);
    k_qgather<<<t64cn + t64ip, 256, 0, stream>>>(
        conn_state, wm1b, bm1, P1, srcs1, off1, cnt1, sum1, N_CONN, t64cn,
        ip_state, wm2b, bm2, P2, srcs2, off2, cnt2, sum2, N_IP);
    k_gru_fused<<<t128cn + t128ip, 256, 0, stream>>>(
        sum1, gckb, gcrb, gcb, conn_state, N_CONN, t128cn,
        sum2, gikb, girb, gib, ip_state, N_IP);
  }

  k_readout2<<<t64cn, 256, 0, stream>>>(conn_state, wr1b, br1, wr2b, br2,
                                        Wr3, br3, out, N_CONN);
}

// Round 10
// 549.683 us; speedup vs baseline: 1.2194x; 1.0109x over previous
//
#include <hip/hip_runtime.h>
#include <math.h>

#define D 128
#define NF 10
#define N_IP 20000
#define N_CONN 100000
#define NE 200000
#define T_ROUNDS 3

typedef unsigned short u16;
using bf16x8 = __attribute__((ext_vector_type(8))) short;
using floatx4 = __attribute__((ext_vector_type(4))) float;

__device__ inline u16 f2bf(float f) {
  union { float f; unsigned u; } v; v.f = f;
  unsigned u = v.u;
  return (u16)((u + 0x7fffu + ((u >> 16) & 1u)) >> 16);  // RNE
}
__device__ inline float bf2f(u16 h) {
  union { unsigned u; float f; } v; v.u = ((unsigned)h) << 16; return v.f;
}

__device__ inline float fsigmoid(float s) { return 1.f / (1.f + __expf(-s)); }
__device__ inline float ftanh(float a) {
  a = fminf(fmaxf(a, -15.f), 15.f);
  float e = __expf(2.f * a);
  return (e - 1.f) / (e + 1.f);
}

// ---------------- fused init: states + cnt zero ----------------
__global__ void k_init_all(u16* __restrict__ ip_state, u16* __restrict__ conn_state,
                           const float* __restrict__ feat, int* __restrict__ cnt) {
  int i = blockIdx.x * blockDim.x + threadIdx.x;
  const int nip = N_IP * D;
  const int nstate = (N_IP + N_CONN) * D;
  if (i < nip) {
    ip_state[i] = 0x3F80;  // bf16(1.0)
  } else if (i < nstate) {
    int j = i - nip;
    int r = j >> 7, c = j & 127;
    conn_state[j] = (c < NF) ? f2bf(feat[r * NF + c]) : (u16)0;
  }
  if (i < N_CONN + N_IP) cnt[i] = 0;
}

// ---------------- fused weight prep (all matrices, bf16 [col][k]) ----------------
__global__ void k_prep_all(
    const float* __restrict__ gik, const float* __restrict__ gir,
    const float* __restrict__ gck, const float* __restrict__ gcr,
    const float* __restrict__ Wm1, const float* __restrict__ Wm2,
    const float* __restrict__ Wr1, const float* __restrict__ Wr2,
    u16* __restrict__ gikb, u16* __restrict__ girb,
    u16* __restrict__ gckb, u16* __restrict__ gcrb,
    u16* __restrict__ wm1b, u16* __restrict__ wm2b,
    u16* __restrict__ wm1t, u16* __restrict__ wm2t,
    u16* __restrict__ wr1b, u16* __restrict__ wr2b) {
  int i = blockIdx.x * blockDim.x + threadIdx.x;
  if (i < 196608) {  // 4 GRU mats (128x384 -> [col][k] 384x128)
    int m = i / 49152, r = i % 49152;
    const float* W = (m == 0) ? gik : (m == 1) ? gir : (m == 2) ? gck : gcr;
    u16* Wb = (m == 0) ? gikb : (m == 1) ? girb : (m == 2) ? gckb : gcrb;
    int col = r >> 7, k = r & 127;
    Wb[r] = f2bf(W[k * 384 + col]);
  } else if (i < 278528) {  // 5 x 128x128 blocks
    int j = i - 196608;
    int m = j / 16384, r = j % 16384;
    const float* W; u16* Wb; int k0;
    if (m == 0) { W = Wm1; Wb = wm1b; k0 = 128; }
    else if (m == 1) { W = Wm2; Wb = wm2b; k0 = 128; }
    else if (m == 2) { W = Wm1; Wb = wm1t; k0 = 0; }
    else if (m == 3) { W = Wm2; Wb = wm2t; k0 = 0; }
    else { W = Wr1; Wb = wr1b; k0 = 0; }
    int col = r >> 7, k = r & 127;
    Wb[r] = f2bf(W[(k0 + k) * 128 + col]);
  } else if (i < 286720) {  // Wr2 128x64 -> [col][k] 64x128
    int r = i - 278528;
    int col = r >> 7, k = r & 127;
    wr2b[r] = f2bf(Wr2[k * 64 + col]);
  }
}

__global__ void k_count(const int* __restrict__ d1, const int* __restrict__ d2,
                        int* __restrict__ c1, int* __restrict__ c2) {
  int e = blockIdx.x * blockDim.x + threadIdx.x;
  if (e >= NE) return;
  atomicAdd(&c1[d1[e]], 1);
  atomicAdd(&c2[d2[e]], 1);
}

// ---------------- merged 3-pass exclusive scan (both segment arrays) ----------------
__global__ void k_scan_part2(const int* __restrict__ cnt1, int* __restrict__ bsum1,
                             int n1, int nb1,
                             const int* __restrict__ cnt2, int* __restrict__ bsum2, int n2) {
  const int* cnt; int* bsum; int n, b;
  if ((int)blockIdx.x < nb1) { cnt = cnt1; bsum = bsum1; n = n1; b = blockIdx.x; }
  else { cnt = cnt2; bsum = bsum2; n = n2; b = blockIdx.x - nb1; }
  int t = threadIdx.x;
  int base = b * 1024 + t * 4;
  int s = 0;
#pragma unroll
  for (int i = 0; i < 4; i++) { int j = base + i; if (j < n) s += cnt[j]; }
  for (int d = 32; d > 0; d >>= 1) s += __shfl_xor(s, d, 64);
  __shared__ int wred[4];
  int lane = t & 63, wv = t >> 6;
  if (lane == 0) wred[wv] = s;
  __syncthreads();
  if (t == 0) bsum[b] = wred[0] + wred[1] + wred[2] + wred[3];
}

__device__ inline void scan_mid_body(int* bsum, int m, int t) {
  int v = (t < m) ? bsum[t] : 0;
  int lane = t & 63, wv = t >> 6;
  int x = v;
  for (int d = 1; d < 64; d <<= 1) { int y = __shfl_up(x, d, 64); if (lane >= d) x += y; }
  __shared__ int wsum[4];
  if (lane == 63) wsum[wv] = x;
  __syncthreads();
  int add = 0;
  for (int i = 0; i < wv; i++) add += wsum[i];
  int ex = add + x - v;
  if (t < m) bsum[t] = ex;
  __syncthreads();
}

__global__ void k_scan_mid2(int* __restrict__ bsum1, int m1, int* __restrict__ bsum2, int m2) {
  int t = threadIdx.x;
  scan_mid_body(bsum1, m1, t);
  scan_mid_body(bsum2, m2, t);
}

// pass 3: write off AND cur (copyint folded in)
__global__ void k_scan_final2(const int* __restrict__ cnt1, const int* __restrict__ bsum1,
                              int* __restrict__ off1, int* __restrict__ cur1, int n1, int nb1,
                              const int* __restrict__ cnt2, const int* __restrict__ bsum2,
                              int* __restrict__ off2, int* __restrict__ cur2, int n2) {
  const int* cnt; const int* bsum; int* off; int* cur; int n, b;
  if ((int)blockIdx.x < nb1) {
    cnt = cnt1; bsum = bsum1; off = off1; cur = cur1; n = n1; b = blockIdx.x;
  } else {
    cnt = cnt2; bsum = bsum2; off = off2; cur = cur2; n = n2; b = blockIdx.x - nb1;
  }
  int t = threadIdx.x;
  int base = b * 1024 + t * 4;
  int vals[4]; int s = 0;
#pragma unroll
  for (int i = 0; i < 4; i++) {
    int j = base + i;
    vals[i] = (j < n) ? cnt[j] : 0;
    s += vals[i];
  }
  int lane = t & 63, wv = t >> 6;
  int x = s;
  for (int d = 1; d < 64; d <<= 1) { int y = __shfl_up(x, d, 64); if (lane >= d) x += y; }
  __shared__ int wsum[4];
  if (lane == 63) wsum[wv] = x;
  __syncthreads();
  int add = 0;
  for (int i = 0; i < wv; i++) add += wsum[i];
  int run = add + x - s + bsum[b];
#pragma unroll
  for (int i = 0; i < 4; i++) {
    int j = base + i;
    if (j < n) { off[j] = run; cur[j] = run; }
    run += vals[i];
  }
}

__global__ void k_scatter(const int* __restrict__ s1, const int* __restrict__ d1,
                          const int* __restrict__ s2, const int* __restrict__ d2,
                          int* __restrict__ cur1, int* __restrict__ cur2,
                          int* __restrict__ o1, int* __restrict__ o2) {
  int e = blockIdx.x * blockDim.x + threadIdx.x;
  if (e >= NE) return;
  int p1 = atomicAdd(&cur1[d1[e]], 1);
  o1[p1] = s1[e];
  int p2 = atomicAdd(&cur2[d2[e]], 1);
  o2[p2] = s2[e];
}

// ---------------- merged P-GEMM (bf16 in/out): P = S @ Wt^T ----------------
__global__ __launch_bounds__(256) void k_gemmP(
    const u16* __restrict__ S1, const u16* __restrict__ Wt1, u16* __restrict__ P1,
    int M1, int tiles1,
    const u16* __restrict__ S2, const u16* __restrict__ Wt2, u16* __restrict__ P2,
    int M2) {
  __shared__ __align__(16) u16 Wls[128 * 128];  // 32KB; reused as C (64x136)
  const u16* S; const u16* Wt; u16* P; int M, bm;
  if ((int)blockIdx.x < tiles1) { S = S1; Wt = Wt1; P = P1; M = M1; bm = blockIdx.x * 64; }
  else { S = S2; Wt = Wt2; P = P2; M = M2; bm = (blockIdx.x - tiles1) * 64; }
  const int tid = threadIdx.x, wv = tid >> 6, lane = tid & 63;
  const int lrow = lane & 15, quad = lane >> 4;
#pragma unroll
  for (int i = 0; i < 8; i++) {  // stage W swizzled
    int task = i * 256 + tid;
    int col = task >> 4, gr = task & 15;
    uint4 v = *(const uint4*)(Wt + (size_t)col * 128 + gr * 8);
    *(uint4*)(Wls + (size_t)col * 128 + ((gr ^ (col & 15)) * 8)) = v;
  }
  const int arow = bm + wv * 16 + lrow;
  const bool arv = arow < M;
  const bf16x8 zv = {0, 0, 0, 0, 0, 0, 0, 0};
  bf16x8 a[4];
#pragma unroll
  for (int ks = 0; ks < 4; ks++)
    a[ks] = arv ? *(const bf16x8*)(S + (size_t)arow * 128 + quad * 8 + ks * 32) : zv;
  __syncthreads();
  floatx4 acc[8];
#pragma unroll
  for (int ct = 0; ct < 8; ct++) acc[ct] = {0.f, 0.f, 0.f, 0.f};
#pragma unroll
  for (int ks = 0; ks < 4; ks++) {
#pragma unroll
    for (int ct = 0; ct < 8; ct++) {
      int col = ct * 16 + lrow;
      bf16x8 b = *(const bf16x8*)(Wls + (size_t)col * 128 + (((4 * ks + quad) ^ lrow) * 8));
      acc[ct] = __builtin_amdgcn_mfma_f32_16x16x32_bf16(a[ks], b, acc[ct], 0, 0, 0);
    }
  }
  __syncthreads();  // W reads done; reuse as C
  u16* Cls = Wls;   // 64 x 136
#pragma unroll
  for (int ct = 0; ct < 8; ct++) {
    int col = ct * 16 + lrow;
#pragma unroll
    for (int reg = 0; reg < 4; reg++) {
      int lr = wv * 16 + quad * 4 + reg;
      Cls[(size_t)lr * 136 + col] = f2bf(acc[ct][reg]);
    }
  }
  __syncthreads();
#pragma unroll
  for (int i = 0; i < 4; i++) {  // coalesced bf16 write-out
    int task = i * 256 + tid;
    int row = task >> 4, c8 = task & 15;
    int gr2 = bm + row;
    if (gr2 < M)
      *(uint4*)(P + (size_t)gr2 * 128 + c8 * 8) = *(const uint4*)(Cls + (size_t)row * 136 + c8 * 8);
  }
}

// ---------------- merged fused Q-GEMM + gather-mean (bf16 in/out) ----------------
__global__ __launch_bounds__(256) void k_qgather(
    const u16* __restrict__ S1, const u16* __restrict__ Wb1, const float* __restrict__ bias1,
    const u16* __restrict__ P1g, const int* __restrict__ srcs1g,
    const int* __restrict__ off1g, const int* __restrict__ cnt1g,
    u16* __restrict__ out1, int n1, int tiles1,
    const u16* __restrict__ S2, const u16* __restrict__ Wb2, const float* __restrict__ bias2,
    const u16* __restrict__ P2g, const int* __restrict__ srcs2g,
    const int* __restrict__ off2g, const int* __restrict__ cnt2g,
    u16* __restrict__ out2, int n2) {
  __shared__ __align__(16) char smem[64 * 132 * 4];  // 33792 B
  u16* Wls = (u16*)smem;
  float* Qls = (float*)smem;
  const u16* S; const u16* Wb; const float* bias; const u16* P;
  const int* srcs; const int* off; const int* cnt; u16* outm; int nnodes, bm;
  if ((int)blockIdx.x < tiles1) {
    S = S1; Wb = Wb1; bias = bias1; P = P1g; srcs = srcs1g; off = off1g; cnt = cnt1g;
    outm = out1; nnodes = n1; bm = blockIdx.x * 64;
  } else {
    S = S2; Wb = Wb2; bias = bias2; P = P2g; srcs = srcs2g; off = off2g; cnt = cnt2g;
    outm = out2; nnodes = n2; bm = (blockIdx.x - tiles1) * 64;
  }
  const int tid = threadIdx.x, wv = tid >> 6, lane = tid & 63;
  const int lrow = lane & 15, quad = lane >> 4;
#pragma unroll
  for (int i = 0; i < 8; i++) {  // stage W swizzled
    int task = i * 256 + tid;
    int col = task >> 4, gr = task & 15;
    uint4 v = *(const uint4*)(Wb + (size_t)col * 128 + gr * 8);
    *(uint4*)(Wls + (size_t)col * 128 + ((gr ^ (col & 15)) * 8)) = v;
  }
  const int arow = bm + wv * 16 + lrow;
  const bool arv = arow < nnodes;
  const bf16x8 zv = {0, 0, 0, 0, 0, 0, 0, 0};
  bf16x8 a[4];
#pragma unroll
  for (int ks = 0; ks < 4; ks++)
    a[ks] = arv ? *(const bf16x8*)(S + (size_t)arow * 128 + quad * 8 + ks * 32) : zv;
  __syncthreads();
  floatx4 acc[8];
#pragma unroll
  for (int ct = 0; ct < 8; ct++) acc[ct] = {0.f, 0.f, 0.f, 0.f};
#pragma unroll
  for (int ks = 0; ks < 4; ks++) {
#pragma unroll
    for (int ct = 0; ct < 8; ct++) {
      int col = ct * 16 + lrow;
      bf16x8 b = *(const bf16x8*)(Wls + (size_t)col * 128 + (((4 * ks + quad) ^ lrow) * 8));
      acc[ct] = __builtin_amdgcn_mfma_f32_16x16x32_bf16(a[ks], b, acc[ct], 0, 0, 0);
    }
  }
  __syncthreads();  // W reads done; reuse smem as Q (fp32, stride 132)
#pragma unroll
  for (int ct = 0; ct < 8; ct++) {
    int col = ct * 16 + lrow;
    float bv = bias[col];
#pragma unroll
    for (int reg = 0; reg < 4; reg++) {
      int lr = wv * 16 + quad * 4 + reg;
      Qls[(size_t)lr * 132 + col] = acc[ct][reg] + bv;
    }
  }
  __syncthreads();
  // gather: 64 nodes x 16 col-granules (8 bf16 each) = 1024 tasks
#pragma unroll
  for (int it = 0; it < 4; it++) {
    int task = it * 256 + tid;
    int nl = task >> 4, c8 = (task & 15) << 3;
    int node = bm + nl;
    if (node >= nnodes) continue;
    const float* qp = Qls + (size_t)nl * 132 + c8;
    float4 qa = *(const float4*)(qp);
    float4 qb = *(const float4*)(qp + 4);
    float q[8] = {qa.x, qa.y, qa.z, qa.w, qb.x, qb.y, qb.z, qb.w};
    float acg[8] = {0.f, 0.f, 0.f, 0.f, 0.f, 0.f, 0.f, 0.f};
    int o = off[node], n = cnt[node];
    int i = 0;
    for (; i + 4 <= n; i += 4) {
      int s0 = srcs[o + i], s1 = srcs[o + i + 1], s2 = srcs[o + i + 2], s3 = srcs[o + i + 3];
      uint4 v0 = *(const uint4*)(P + (size_t)s0 * 128 + c8);
      uint4 v1 = *(const uint4*)(P + (size_t)s1 * 128 + c8);
      uint4 v2 = *(const uint4*)(P + (size_t)s2 * 128 + c8);
      uint4 v3 = *(const uint4*)(P + (size_t)s3 * 128 + c8);
      unsigned w[16] = {v0.x, v0.y, v0.z, v0.w, v1.x, v1.y, v1.z, v1.w,
                        v2.x, v2.y, v2.z, v2.w, v3.x, v3.y, v3.z, v3.w};
#pragma unroll
      for (int e = 0; e < 4; e++)
#pragma unroll
        for (int k = 0; k < 4; k++) {
          unsigned ww = w[e * 4 + k];
          float lo = __uint_as_float(ww << 16);
          float hi = __uint_as_float(ww & 0xffff0000u);
          acg[2 * k] += fmaxf(lo + q[2 * k], 0.f);
          acg[2 * k + 1] += fmaxf(hi + q[2 * k + 1], 0.f);
        }
    }
    for (; i < n; i++) {
      int s0 = srcs[o + i];
      uint4 v0 = *(const uint4*)(P + (size_t)s0 * 128 + c8);
      unsigned w[4] = {v0.x, v0.y, v0.z, v0.w};
#pragma unroll
      for (int k = 0; k < 4; k++) {
        unsigned ww = w[k];
        float lo = __uint_as_float(ww << 16);
        float hi = __uint_as_float(ww & 0xffff0000u);
        acg[2 * k] += fmaxf(lo + q[2 * k], 0.f);
        acg[2 * k + 1] += fmaxf(hi + q[2 * k + 1], 0.f);
      }
    }
    float inv = 1.f / fmaxf((float)n, 1.f);
    bf16x8 ov;
#pragma unroll
    for (int k = 0; k < 8; k++) ov[k] = (short)f2bf(acg[k] * inv);
    *(bf16x8*)(outm + (size_t)node * 128 + c8) = ov;
  }
}

// ---------------- merged fused GRU v8: 64 rows/block, H staged in LDS ----------------
// Kills scattered global 2B H loads/stores (round-9 latency bottleneck): H block
// lives in LDS (granule-XOR swizzle), global H = one coalesced read + one write.
// LDS 24.6K (weights) + 16K (H) = 40.96 KB -> 4 blocks/CU; live regs ~72.
__global__ __launch_bounds__(256, 4) void k_gru_fused(
    const u16* __restrict__ X1, const u16* __restrict__ Wx1, const u16* __restrict__ Wh1,
    const float* __restrict__ b1, u16* __restrict__ H1, int r1, int tiles1,
    const u16* __restrict__ X2, const u16* __restrict__ Wx2, const u16* __restrict__ Wh2,
    const float* __restrict__ b2, u16* __restrict__ H2, int r2) {
  __shared__ __align__(16) u16 Wls[6 * 16 * 128];  // 24576 B
  __shared__ __align__(16) u16 Hls[64 * 128];      // 16384 B, swizzled g^=(row&15)
  const u16* X; const u16* Wxb; const u16* Whb; const float* bias; u16* H;
  int rows, bm;
  if ((int)blockIdx.x < tiles1) {
    X = X1; Wxb = Wx1; Whb = Wh1; bias = b1; H = H1; rows = r1; bm = blockIdx.x * 64;
  } else {
    X = X2; Wxb = Wx2; Whb = Wh2; bias = b2; H = H2; rows = r2;
    bm = (blockIdx.x - tiles1) * 64;
  }
  const int tid = threadIdx.x, wv = tid >> 6, lane = tid & 63;
  const int lrow = lane & 15, quad = lane >> 4;
  const bf16x8 zv = {0, 0, 0, 0, 0, 0, 0, 0};
  const uint4 z4 = {0, 0, 0, 0};
  // stage H into LDS (coalesced read, swizzled store); 64x16 granules = 1024 tasks
#pragma unroll
  for (int i = 0; i < 4; i++) {
    int task = i * 256 + tid;
    int row = task >> 4, g = task & 15;
    int grow = bm + row;
    uint4 v = (grow < rows) ? *(const uint4*)(H + (size_t)grow * 128 + g * 8) : z4;
    *(uint4*)(Hls + (size_t)row * 128 + ((g ^ (row & 15)) * 8)) = v;
  }
  // X A-frags direct from global (coalesced)
  const int arow = bm + wv * 16 + lrow;
  const bool arv = arow < rows;
  bf16x8 ax[4];
#pragma unroll
  for (int ks = 0; ks < 4; ks++)
    ax[ks] = arv ? *(const bf16x8*)(X + (size_t)arow * 128 + quad * 8 + ks * 32) : zv;
  __syncthreads();
  // ah A-frags from LDS H (2-way conflicts = free)
  bf16x8 ah[4];
#pragma unroll
  for (int ks = 0; ks < 4; ks++)
    ah[ks] = *(const bf16x8*)(Hls + (size_t)(wv * 16 + lrow) * 128 + (((ks * 4 + quad) ^ lrow) * 8));
  const int lr0 = wv * 16 + quad * 4;  // local row base for epilogue (+reg)
  for (int ch = 0; ch < 8; ch++) {
    __syncthreads();  // prev chunk's Wls readers done (also covers ah reads on ch=0)
    // stage weights: 1536 uint4 tasks, 2 passes x 3/thread
#pragma unroll
    for (int p = 0; p < 2; p++) {
      uint4 v[3];
#pragma unroll
      for (int j = 0; j < 3; j++) {
        int task = (p * 3 + j) * 256 + tid;
        int seg = task >> 8, rem = task & 255;
        int col = rem >> 4, gr = rem & 15;
        const u16* gsrc = (seg < 3 ? Wxb : Whb) +
                          (size_t)((seg < 3 ? seg : seg - 3) * 128 + ch * 16 + col) * 128 + gr * 8;
        v[j] = *(const uint4*)gsrc;
      }
#pragma unroll
      for (int j = 0; j < 3; j++) {
        int task = (p * 3 + j) * 256 + tid;
        int seg = task >> 8, rem = task & 255;
        int col = rem >> 4, gr = rem & 15;
        *(uint4*)(Wls + (size_t)(seg * 16 + col) * 128 + ((gr ^ col) * 8)) = v[j];
      }
    }
    __syncthreads();
    floatx4 acc[3][2];  // gate, x/h -> 24 VGPRs
#pragma unroll
    for (int g = 0; g < 3; g++) {
      acc[g][0] = {0.f, 0.f, 0.f, 0.f};
      acc[g][1] = {0.f, 0.f, 0.f, 0.f};
    }
#pragma unroll
    for (int ks = 0; ks < 4; ks++) {
      int posu = ((4 * ks + quad) ^ lrow) * 8;
#pragma unroll
      for (int g = 0; g < 3; g++) {
        bf16x8 bx = *(const bf16x8*)(Wls + (size_t)(g * 16 + lrow) * 128 + posu);
        bf16x8 bh = *(const bf16x8*)(Wls + (size_t)((3 + g) * 16 + lrow) * 128 + posu);
        acc[g][0] = __builtin_amdgcn_mfma_f32_16x16x32_bf16(ax[ks], bx, acc[g][0], 0, 0, 0);
        acc[g][1] = __builtin_amdgcn_mfma_f32_16x16x32_bf16(ah[ks], bh, acc[g][1], 0, 0, 0);
      }
    }
    int hcol = ch * 16 + lrow;
    float bxz = bias[hcol];
    float bxr = bias[128 + hcol];
    float bxh = bias[256 + hcol];
    float bhz = bias[384 + hcol];
    float bhr = bias[384 + 128 + hcol];
    float bhh = bias[384 + 256 + hcol];
    // h_old/h_new via LDS (own wave's rows only -> no cross-wave hazard)
    int ggr = 2 * ch + (lrow >> 3);  // granule of col hcol
    int gel = lrow & 7;              // element within granule
#pragma unroll
    for (int reg = 0; reg < 4; reg++) {
      int lr = lr0 + reg;
      float xz = acc[0][0][reg] + bxz;
      float xr = acc[1][0][reg] + bxr;
      float xh = acc[2][0][reg] + bxh;
      float hz = acc[0][1][reg] + bhz;
      float hr = acc[1][1][reg] + bhr;
      float hh = acc[2][1][reg] + bhh;
      float z = fsigmoid(xz + hz);
      float rr = fsigmoid(xr + hr);
      float hc = ftanh(xh + rr * hh);
      u16* hp = Hls + (size_t)lr * 128 + ((ggr ^ (lr & 15)) * 8) + gel;
      float hold = bf2f(*hp);
      *hp = f2bf(z * hold + (1.f - z) * hc);
    }
  }
  __syncthreads();
  // coalesced write-out
#pragma unroll
  for (int i = 0; i < 4; i++) {
    int task = i * 256 + tid;
    int row = task >> 4, g = task & 15;
    int grow = bm + row;
    if (grow < rows)
      *(uint4*)(H + (size_t)grow * 128 + g * 8) =
          *(const uint4*)(Hls + (size_t)row * 128 + ((g ^ (row & 15)) * 8));
  }
}

// ---------------- fully fused readout: 2 GEMMs + logits + softmax ----------------
__global__ __launch_bounds__(256) void k_readout2(
    const u16* __restrict__ S, const u16* __restrict__ W1b, const float* __restrict__ b1,
    const u16* __restrict__ W2b, const float* __restrict__ b2,
    const float* __restrict__ W3, const float* __restrict__ b3,
    float* __restrict__ out, int M) {
  __shared__ __align__(16) char smem[64 * 132 * 4];  // 33792 B
  u16* Wls = (u16*)smem;                 // phase1: W1 32KB swizzled
  u16* H1ls = (u16*)smem;                // phase2/3: 64 x 136 u16
  u16* W2ls = (u16*)(smem + 17408);      // 64 x 128 u16
  u16* H2ls = (u16*)smem;                // phase4/5: 64 x 72 u16
  float* W3ls = (float*)(smem + 9216);
  float* b3ls = (float*)(smem + 9216 + 3840);
  const int tid = threadIdx.x, wv = tid >> 6, lane = tid & 63;
  const int lrow = lane & 15, quad = lane >> 4;
  const int bm = blockIdx.x * 64;
#pragma unroll
  for (int i = 0; i < 8; i++) {
    int task = i * 256 + tid;
    int col = task >> 4, gr = task & 15;
    uint4 v = *(const uint4*)(W1b + (size_t)col * 128 + gr * 8);
    *(uint4*)(Wls + (size_t)col * 128 + ((gr ^ (col & 15)) * 8)) = v;
  }
  const int arow = bm + wv * 16 + lrow;
  const bool arv = arow < M;
  const bf16x8 zv = {0, 0, 0, 0, 0, 0, 0, 0};
  bf16x8 a[4];
#pragma unroll
  for (int ks = 0; ks < 4; ks++)
    a[ks] = arv ? *(const bf16x8*)(S + (size_t)arow * 128 + quad * 8 + ks * 32) : zv;
  __syncthreads();
  floatx4 acc1[8];
#pragma unroll
  for (int ct = 0; ct < 8; ct++) acc1[ct] = {0.f, 0.f, 0.f, 0.f};
#pragma unroll
  for (int ks = 0; ks < 4; ks++) {
#pragma unroll
    for (int ct = 0; ct < 8; ct++) {
      int col = ct * 16 + lrow;
      bf16x8 b = *(const bf16x8*)(Wls + (size_t)col * 128 + (((4 * ks + quad) ^ lrow) * 8));
      acc1[ct] = __builtin_amdgcn_mfma_f32_16x16x32_bf16(a[ks], b, acc1[ct], 0, 0, 0);
    }
  }
  __syncthreads();
#pragma unroll
  for (int ct = 0; ct < 8; ct++) {
    int col = ct * 16 + lrow;
    float bv = b1[col];
#pragma unroll
    for (int reg = 0; reg < 4; reg++) {
      int lr = wv * 16 + quad * 4 + reg;
      H1ls[(size_t)lr * 136 + col] = f2bf(fmaxf(acc1[ct][reg] + bv, 0.f));
    }
  }
#pragma unroll
  for (int i = 0; i < 4; i++) {
    int task = i * 256 + tid;
    int col = task >> 4, gr = task & 15;
    uint4 v = *(const uint4*)(W2b + (size_t)col * 128 + gr * 8);
    *(uint4*)(W2ls + (size_t)col * 128 + ((gr ^ (col & 15)) * 8)) = v;
  }
  __syncthreads();
  bf16x8 a2[4];
#pragma unroll
  for (int ks = 0; ks < 4; ks++)
    a2[ks] = *(const bf16x8*)(H1ls + (size_t)(wv * 16 + lrow) * 136 + quad * 8 + ks * 32);
  floatx4 acc2[4];
#pragma unroll
  for (int ct = 0; ct < 4; ct++) acc2[ct] = {0.f, 0.f, 0.f, 0.f};
#pragma unroll
  for (int ks = 0; ks < 4; ks++) {
#pragma unroll
    for (int ct = 0; ct < 4; ct++) {
      int col = ct * 16 + lrow;
      bf16x8 b = *(const bf16x8*)(W2ls + (size_t)col * 128 + (((4 * ks + quad) ^ lrow) * 8));
      acc2[ct] = __builtin_amdgcn_mfma_f32_16x16x32_bf16(a2[ks], b, acc2[ct], 0, 0, 0);
    }
  }
  __syncthreads();
#pragma unroll
  for (int ct = 0; ct < 4; ct++) {
    int col = ct * 16 + lrow;
    float bv = b2[col];
#pragma unroll
    for (int reg = 0; reg < 4; reg++) {
      int lr = wv * 16 + quad * 4 + reg;
      H2ls[(size_t)lr * 72 + col] = f2bf(fmaxf(acc2[ct][reg] + bv, 0.f));
    }
  }
  for (int l = tid; l < 960; l += 256) W3ls[l] = W3[l];
  if (tid < 15) b3ls[tid] = b3[tid];
  __syncthreads();
  if (tid < 64) {
    int row = tid, gr2 = bm + row;
    if (gr2 < M) {
      float lg[15];
#pragma unroll
      for (int c = 0; c < 15; c++) lg[c] = b3ls[c];
      for (int k = 0; k < 64; k++) {
        float hk = bf2f(H2ls[(size_t)row * 72 + k]);
#pragma unroll
        for (int c = 0; c < 15; c++) lg[c] += hk * W3ls[k * 15 + c];
      }
      float m = lg[0];
#pragma unroll
      for (int c = 1; c < 15; c++) m = fmaxf(m, lg[c]);
      float ssum = 0.f;
#pragma unroll
      for (int c = 0; c < 15; c++) { lg[c] = __expf(lg[c] - m); ssum += lg[c]; }
      float inv = 1.f / ssum;
#pragma unroll
      for (int c = 0; c < 15; c++) out[(size_t)gr2 * 15 + c] = lg[c] * inv;
    }
  }
}

// ---------------- launch ----------------
extern "C" void kernel_launch(void* const* d_in, const int* in_sizes, int n_in,
                              void* d_out, int out_size, void* d_ws, size_t ws_size,
                              hipStream_t stream) {
  const float* feat = (const float*)d_in[0];
  const int* src1 = (const int*)d_in[1];
  const int* dst1 = (const int*)d_in[2];
  const int* src2 = (const int*)d_in[3];
  const int* dst2 = (const int*)d_in[4];
  const float* Wm1 = (const float*)d_in[5];
  const float* bm1 = (const float*)d_in[6];
  const float* Wm2 = (const float*)d_in[7];
  const float* bm2 = (const float*)d_in[8];
  const float* gik = (const float*)d_in[9];
  const float* gir = (const float*)d_in[10];
  const float* gib = (const float*)d_in[11];
  const float* gck = (const float*)d_in[12];
  const float* gcr = (const float*)d_in[13];
  const float* gcb = (const float*)d_in[14];
  const float* Wr1 = (const float*)d_in[15];
  const float* br1 = (const float*)d_in[16];
  const float* Wr2 = (const float*)d_in[17];
  const float* br2 = (const float*)d_in[18];
  const float* Wr3 = (const float*)d_in[19];
  const float* br3 = (const float*)d_in[20];
  float* out = (float*)d_out;

  // ---- workspace layout (u16 units) ----
  u16* w16 = (u16*)d_ws;
  size_t o = 0;
  u16* ip_state = w16 + o;   o += (size_t)N_IP * D;
  u16* conn_state = w16 + o; o += (size_t)N_CONN * D;
  u16* sum1 = w16 + o;       o += (size_t)N_CONN * D;
  u16* sum2 = w16 + o;       o += (size_t)N_IP * D;
  u16* P1 = w16 + o;         o += (size_t)N_IP * D;
  u16* P2 = w16 + o;         o += (size_t)N_CONN * D;
  u16* gikb = w16 + o;       o += 49152;
  u16* girb = w16 + o;       o += 49152;
  u16* gckb = w16 + o;       o += 49152;
  u16* gcrb = w16 + o;       o += 49152;
  u16* wm1b = w16 + o;       o += 16384;
  u16* wm2b = w16 + o;       o += 16384;
  u16* wm1t = w16 + o;       o += 16384;
  u16* wm2t = w16 + o;       o += 16384;
  u16* wr1b = w16 + o;       o += 16384;
  u16* wr2b = w16 + o;       o += 8192;
  int* ip = (int*)(w16 + o);
  int* cnt1 = ip;  ip += N_CONN;
  int* cnt2 = ip;  ip += N_IP;
  int* off1 = ip;  ip += N_CONN;
  int* off2 = ip;  ip += N_IP;
  int* cur1 = ip;  ip += N_CONN;
  int* cur2 = ip;  ip += N_IP;
  int* srcs1 = ip; ip += NE;
  int* srcs2 = ip; ip += NE;
  int* bsum1 = ip; ip += 256;
  int* bsum2 = ip; ip += 256;

  const int BT = 256;

  // ---- fused init + weight prep ----
  const int nstate = (N_IP + N_CONN) * D;
  k_init_all<<<(nstate + BT - 1) / BT, BT, 0, stream>>>(ip_state, conn_state, feat, cnt1);
  k_prep_all<<<(286720 + BT - 1) / BT, BT, 0, stream>>>(
      gik, gir, gck, gcr, Wm1, Wm2, Wr1, Wr2,
      gikb, girb, gckb, gcrb, wm1b, wm2b, wm1t, wm2t, wr1b, wr2b);

  // ---- build CSR ----
  k_count<<<(NE + BT - 1) / BT, BT, 0, stream>>>(dst1, dst2, cnt1, cnt2);
  const int nb1 = (N_CONN + 1023) / 1024, nb2 = (N_IP + 1023) / 1024;
  k_scan_part2<<<nb1 + nb2, 256, 0, stream>>>(cnt1, bsum1, N_CONN, nb1, cnt2, bsum2, N_IP);
  k_scan_mid2<<<1, 256, 0, stream>>>(bsum1, nb1, bsum2, nb2);
  k_scan_final2<<<nb1 + nb2, 256, 0, stream>>>(cnt1, bsum1, off1, cur1, N_CONN, nb1,
                                               cnt2, bsum2, off2, cur2, N_IP);
  k_scatter<<<(NE + BT - 1) / BT, BT, 0, stream>>>(src1, dst1, src2, dst2,
                                                   cur1, cur2, srcs1, srcs2);

  const int t64ip = (N_IP + 63) / 64;       // 313
  const int t64cn = (N_CONN + 63) / 64;     // 1563

  for (int t = 0; t < T_ROUNDS; t++) {
    k_gemmP<<<t64ip + t64cn, 256, 0, stream>>>(ip_state, wm1t, P1, N_IP, t64ip,
                                               conn_state, wm2t, P2, N_CONN);
    k_qgather<<<t64cn + t64ip, 256, 0, stream>>>(
        conn_state, wm1b, bm1, P1, srcs1, off1, cnt1, sum1, N_CONN, t64cn,
        ip_state, wm2b, bm2, P2, srcs2, off2, cnt2, sum2, N_IP);
    k_gru_fused<<<t64cn + t64ip, 256, 0, stream>>>(
        sum1, gckb, gcrb, gcb, conn_state, N_CONN, t64cn,
        sum2, gikb, girb, gib, ip_state, N_IP);
  }

  k_readout2<<<t64cn, 256, 0, stream>>>(conn_state, wr1b, br1, wr2b, br2,
                                        Wr3, br3, out, N_CONN);
}

// Round 11
// 524.080 us; speedup vs baseline: 1.2789x; 1.0489x over previous
//
#include <hip/hip_runtime.h>
#include <math.h>

#define D 128
#define NF 10
#define N_IP 20000
#define N_CONN 100000
#define NE 200000
#define T_ROUNDS 3

typedef unsigned short u16;
using bf16x8 = __attribute__((ext_vector_type(8))) short;
using floatx4 = __attribute__((ext_vector_type(4))) float;

__device__ inline u16 f2bf(float f) {
  union { float f; unsigned u; } v; v.f = f;
  unsigned u = v.u;
  return (u16)((u + 0x7fffu + ((u >> 16) & 1u)) >> 16);  // RNE
}
__device__ inline float bf2f(u16 h) {
  union { unsigned u; float f; } v; v.u = ((unsigned)h) << 16; return v.f;
}

__device__ inline float fsigmoid(float s) { return 1.f / (1.f + __expf(-s)); }
__device__ inline float ftanh(float a) {
  a = fminf(fmaxf(a, -15.f), 15.f);
  float e = __expf(2.f * a);
  return (e - 1.f) / (e + 1.f);
}

// ---------------- fused init: states + cnt zero ----------------
__global__ void k_init_all(u16* __restrict__ ip_state, u16* __restrict__ conn_state,
                           const float* __restrict__ feat, int* __restrict__ cnt) {
  int i = blockIdx.x * blockDim.x + threadIdx.x;
  const int nip = N_IP * D;
  const int nstate = (N_IP + N_CONN) * D;
  if (i < nip) {
    ip_state[i] = 0x3F80;  // bf16(1.0)
  } else if (i < nstate) {
    int j = i - nip;
    int r = j >> 7, c = j & 127;
    conn_state[j] = (c < NF) ? f2bf(feat[r * NF + c]) : (u16)0;
  }
  if (i < N_CONN + N_IP) cnt[i] = 0;
}

// ---------------- fused weight prep (all matrices, bf16 [col][k]) ----------------
__global__ void k_prep_all(
    const float* __restrict__ gik, const float* __restrict__ gir,
    const float* __restrict__ gck, const float* __restrict__ gcr,
    const float* __restrict__ Wm1, const float* __restrict__ Wm2,
    const float* __restrict__ Wr1, const float* __restrict__ Wr2,
    u16* __restrict__ gikb, u16* __restrict__ girb,
    u16* __restrict__ gckb, u16* __restrict__ gcrb,
    u16* __restrict__ wm1b, u16* __restrict__ wm2b,
    u16* __restrict__ wm1t, u16* __restrict__ wm2t,
    u16* __restrict__ wr1b, u16* __restrict__ wr2b) {
  int i = blockIdx.x * blockDim.x + threadIdx.x;
  if (i < 196608) {  // 4 GRU mats (128x384 -> [col][k] 384x128)
    int m = i / 49152, r = i % 49152;
    const float* W = (m == 0) ? gik : (m == 1) ? gir : (m == 2) ? gck : gcr;
    u16* Wb = (m == 0) ? gikb : (m == 1) ? girb : (m == 2) ? gckb : gcrb;
    int col = r >> 7, k = r & 127;
    Wb[r] = f2bf(W[k * 384 + col]);
  } else if (i < 278528) {  // 5 x 128x128 blocks
    int j = i - 196608;
    int m = j / 16384, r = j % 16384;
    const float* W; u16* Wb; int k0;
    if (m == 0) { W = Wm1; Wb = wm1b; k0 = 128; }
    else if (m == 1) { W = Wm2; Wb = wm2b; k0 = 128; }
    else if (m == 2) { W = Wm1; Wb = wm1t; k0 = 0; }
    else if (m == 3) { W = Wm2; Wb = wm2t; k0 = 0; }
    else { W = Wr1; Wb = wr1b; k0 = 0; }
    int col = r >> 7, k = r & 127;
    Wb[r] = f2bf(W[(k0 + k) * 128 + col]);
  } else if (i < 286720) {  // Wr2 128x64 -> [col][k] 64x128
    int r = i - 278528;
    int col = r >> 7, k = r & 127;
    wr2b[r] = f2bf(Wr2[k * 64 + col]);
  }
}

__global__ void k_count(const int* __restrict__ d1, const int* __restrict__ d2,
                        int* __restrict__ c1, int* __restrict__ c2) {
  int e = blockIdx.x * blockDim.x + threadIdx.x;
  if (e >= NE) return;
  atomicAdd(&c1[d1[e]], 1);
  atomicAdd(&c2[d2[e]], 1);
}

// ---------------- merged 3-pass exclusive scan (both segment arrays) ----------------
__global__ void k_scan_part2(const int* __restrict__ cnt1, int* __restrict__ bsum1,
                             int n1, int nb1,
                             const int* __restrict__ cnt2, int* __restrict__ bsum2, int n2) {
  const int* cnt; int* bsum; int n, b;
  if ((int)blockIdx.x < nb1) { cnt = cnt1; bsum = bsum1; n = n1; b = blockIdx.x; }
  else { cnt = cnt2; bsum = bsum2; n = n2; b = blockIdx.x - nb1; }
  int t = threadIdx.x;
  int base = b * 1024 + t * 4;
  int s = 0;
#pragma unroll
  for (int i = 0; i < 4; i++) { int j = base + i; if (j < n) s += cnt[j]; }
  for (int d = 32; d > 0; d >>= 1) s += __shfl_xor(s, d, 64);
  __shared__ int wred[4];
  int lane = t & 63, wv = t >> 6;
  if (lane == 0) wred[wv] = s;
  __syncthreads();
  if (t == 0) bsum[b] = wred[0] + wred[1] + wred[2] + wred[3];
}

__device__ inline void scan_mid_body(int* bsum, int m, int t) {
  int v = (t < m) ? bsum[t] : 0;
  int lane = t & 63, wv = t >> 6;
  int x = v;
  for (int d = 1; d < 64; d <<= 1) { int y = __shfl_up(x, d, 64); if (lane >= d) x += y; }
  __shared__ int wsum[4];
  if (lane == 63) wsum[wv] = x;
  __syncthreads();
  int add = 0;
  for (int i = 0; i < wv; i++) add += wsum[i];
  int ex = add + x - v;
  if (t < m) bsum[t] = ex;
  __syncthreads();
}

__global__ void k_scan_mid2(int* __restrict__ bsum1, int m1, int* __restrict__ bsum2, int m2) {
  int t = threadIdx.x;
  scan_mid_body(bsum1, m1, t);
  scan_mid_body(bsum2, m2, t);
}

// pass 3: write off AND cur
__global__ void k_scan_final2(const int* __restrict__ cnt1, const int* __restrict__ bsum1,
                              int* __restrict__ off1, int* __restrict__ cur1, int n1, int nb1,
                              const int* __restrict__ cnt2, const int* __restrict__ bsum2,
                              int* __restrict__ off2, int* __restrict__ cur2, int n2) {
  const int* cnt; const int* bsum; int* off; int* cur; int n, b;
  if ((int)blockIdx.x < nb1) {
    cnt = cnt1; bsum = bsum1; off = off1; cur = cur1; n = n1; b = blockIdx.x;
  } else {
    cnt = cnt2; bsum = bsum2; off = off2; cur = cur2; n = n2; b = blockIdx.x - nb1;
  }
  int t = threadIdx.x;
  int base = b * 1024 + t * 4;
  int vals[4]; int s = 0;
#pragma unroll
  for (int i = 0; i < 4; i++) {
    int j = base + i;
    vals[i] = (j < n) ? cnt[j] : 0;
    s += vals[i];
  }
  int lane = t & 63, wv = t >> 6;
  int x = s;
  for (int d = 1; d < 64; d <<= 1) { int y = __shfl_up(x, d, 64); if (lane >= d) x += y; }
  __shared__ int wsum[4];
  if (lane == 63) wsum[wv] = x;
  __syncthreads();
  int add = 0;
  for (int i = 0; i < wv; i++) add += wsum[i];
  int run = add + x - s + bsum[b];
#pragma unroll
  for (int i = 0; i < 4; i++) {
    int j = base + i;
    if (j < n) { off[j] = run; cur[j] = run; }
    run += vals[i];
  }
}

__global__ void k_scatter(const int* __restrict__ s1, const int* __restrict__ d1,
                          const int* __restrict__ s2, const int* __restrict__ d2,
                          int* __restrict__ cur1, int* __restrict__ cur2,
                          int* __restrict__ o1, int* __restrict__ o2) {
  int e = blockIdx.x * blockDim.x + threadIdx.x;
  if (e >= NE) return;
  int p1 = atomicAdd(&cur1[d1[e]], 1);
  o1[p1] = s1[e];
  int p2 = atomicAdd(&cur2[d2[e]], 1);
  o2[p2] = s2[e];
}

// ---------------- merged P-GEMM (bf16 in/out): P = S @ Wt^T ----------------
__global__ __launch_bounds__(256) void k_gemmP(
    const u16* __restrict__ S1, const u16* __restrict__ Wt1, u16* __restrict__ P1,
    int M1, int tiles1,
    const u16* __restrict__ S2, const u16* __restrict__ Wt2, u16* __restrict__ P2,
    int M2) {
  __shared__ __align__(16) u16 Wls[128 * 128];  // 32KB; reused as C (64x136)
  const u16* S; const u16* Wt; u16* P; int M, bm;
  if ((int)blockIdx.x < tiles1) { S = S1; Wt = Wt1; P = P1; M = M1; bm = blockIdx.x * 64; }
  else { S = S2; Wt = Wt2; P = P2; M = M2; bm = (blockIdx.x - tiles1) * 64; }
  const int tid = threadIdx.x, wv = tid >> 6, lane = tid & 63;
  const int lrow = lane & 15, quad = lane >> 4;
#pragma unroll
  for (int i = 0; i < 8; i++) {  // stage W swizzled
    int task = i * 256 + tid;
    int col = task >> 4, gr = task & 15;
    uint4 v = *(const uint4*)(Wt + (size_t)col * 128 + gr * 8);
    *(uint4*)(Wls + (size_t)col * 128 + ((gr ^ (col & 15)) * 8)) = v;
  }
  const int arow = bm + wv * 16 + lrow;
  const bool arv = arow < M;
  const bf16x8 zv = {0, 0, 0, 0, 0, 0, 0, 0};
  bf16x8 a[4];
#pragma unroll
  for (int ks = 0; ks < 4; ks++)
    a[ks] = arv ? *(const bf16x8*)(S + (size_t)arow * 128 + quad * 8 + ks * 32) : zv;
  __syncthreads();
  floatx4 acc[8];
#pragma unroll
  for (int ct = 0; ct < 8; ct++) acc[ct] = {0.f, 0.f, 0.f, 0.f};
#pragma unroll
  for (int ks = 0; ks < 4; ks++) {
#pragma unroll
    for (int ct = 0; ct < 8; ct++) {
      int col = ct * 16 + lrow;
      bf16x8 b = *(const bf16x8*)(Wls + (size_t)col * 128 + (((4 * ks + quad) ^ lrow) * 8));
      acc[ct] = __builtin_amdgcn_mfma_f32_16x16x32_bf16(a[ks], b, acc[ct], 0, 0, 0);
    }
  }
  __syncthreads();  // W reads done; reuse as C
  u16* Cls = Wls;   // 64 x 136
#pragma unroll
  for (int ct = 0; ct < 8; ct++) {
    int col = ct * 16 + lrow;
#pragma unroll
    for (int reg = 0; reg < 4; reg++) {
      int lr = wv * 16 + quad * 4 + reg;
      Cls[(size_t)lr * 136 + col] = f2bf(acc[ct][reg]);
    }
  }
  __syncthreads();
#pragma unroll
  for (int i = 0; i < 4; i++) {  // coalesced bf16 write-out
    int task = i * 256 + tid;
    int row = task >> 4, c8 = task & 15;
    int gr2 = bm + row;
    if (gr2 < M)
      *(uint4*)(P + (size_t)gr2 * 128 + c8 * 8) = *(const uint4*)(Cls + (size_t)row * 136 + c8 * 8);
  }
}

// ---------------- fused message+GRU: Q-GEMM + gather-mean + GRU, per 64-node block ----------------
// state staged to LDS once (ah frags feed BOTH the Q-GEMM and the GRU h-GEMM);
// mean never leaves LDS (X). LDS: region0 32KB (Wq -> Qb16+Xb -> Wg chunk) + Hls 16KB = 49152.
__global__ __launch_bounds__(256, 2) void k_msggru(
    u16* __restrict__ st1, const u16* __restrict__ wq1, const float* __restrict__ qb1,
    const u16* __restrict__ P1g, const int* __restrict__ srcs1g,
    const int* __restrict__ off1g, const int* __restrict__ cnt1g,
    const u16* __restrict__ wx1, const u16* __restrict__ wh1, const float* __restrict__ gb1,
    int r1, int tiles1,
    u16* __restrict__ st2, const u16* __restrict__ wq2, const float* __restrict__ qb2,
    const u16* __restrict__ P2g, const int* __restrict__ srcs2g,
    const int* __restrict__ off2g, const int* __restrict__ cnt2g,
    const u16* __restrict__ wx2, const u16* __restrict__ wh2, const float* __restrict__ gb2,
    int r2) {
  __shared__ __align__(16) char smem[49152];
  u16* Wq = (u16*)smem;                    // phase A: 128x128 bf16 swizzled (32KB)
  u16* Qb = (u16*)smem;                    // phase B: 64x128 bf16 (16KB)
  u16* Xb = (u16*)(smem + 16384);          // phase B: 64x128 bf16 swizzled (16KB)
  u16* Wg = (u16*)smem;                    // phase C: 6x16x128 bf16 swizzled (24KB)
  u16* Hls = (u16*)(smem + 32768);         // 64x128 bf16 swizzled (16KB), whole kernel
  u16* H; const u16* Wqb; const float* qbias; const u16* P;
  const int* srcs; const int* off; const int* cnt;
  const u16* Wxb; const u16* Whb; const float* gbias; int rows, bm;
  if ((int)blockIdx.x < tiles1) {
    H = st1; Wqb = wq1; qbias = qb1; P = P1g; srcs = srcs1g; off = off1g; cnt = cnt1g;
    Wxb = wx1; Whb = wh1; gbias = gb1; rows = r1; bm = blockIdx.x * 64;
  } else {
    H = st2; Wqb = wq2; qbias = qb2; P = P2g; srcs = srcs2g; off = off2g; cnt = cnt2g;
    Wxb = wx2; Whb = wh2; gbias = gb2; rows = r2; bm = (blockIdx.x - tiles1) * 64;
  }
  const int tid = threadIdx.x, wv = tid >> 6, lane = tid & 63;
  const int lrow = lane & 15, quad = lane >> 4;
  const uint4 z4 = {0, 0, 0, 0};
  // --- phase A: stage Wq (swizzled) + H (swizzled) ---
#pragma unroll
  for (int i = 0; i < 8; i++) {
    int task = i * 256 + tid;
    int col = task >> 4, gr = task & 15;
    uint4 v = *(const uint4*)(Wqb + (size_t)col * 128 + gr * 8);
    *(uint4*)(Wq + (size_t)col * 128 + ((gr ^ (col & 15)) * 8)) = v;
  }
#pragma unroll
  for (int i = 0; i < 4; i++) {
    int task = i * 256 + tid;
    int row = task >> 4, g = task & 15;
    int grow = bm + row;
    uint4 v = (grow < rows) ? *(const uint4*)(H + (size_t)grow * 128 + g * 8) : z4;
    *(uint4*)(Hls + (size_t)row * 128 + ((g ^ (row & 15)) * 8)) = v;
  }
  __syncthreads();
  // state A-frags (serve Q-GEMM and GRU h-GEMM)
  bf16x8 ah[4];
#pragma unroll
  for (int ks = 0; ks < 4; ks++)
    ah[ks] = *(const bf16x8*)(Hls + (size_t)(wv * 16 + lrow) * 128 + (((ks * 4 + quad) ^ lrow) * 8));
  // --- Q-GEMM: Q = state @ Wq^T ---
  floatx4 acc[8];
#pragma unroll
  for (int ct = 0; ct < 8; ct++) acc[ct] = {0.f, 0.f, 0.f, 0.f};
#pragma unroll
  for (int ks = 0; ks < 4; ks++) {
#pragma unroll
    for (int ct = 0; ct < 8; ct++) {
      int col = ct * 16 + lrow;
      bf16x8 b = *(const bf16x8*)(Wq + (size_t)col * 128 + (((4 * ks + quad) ^ lrow) * 8));
      acc[ct] = __builtin_amdgcn_mfma_f32_16x16x32_bf16(ah[ks], b, acc[ct], 0, 0, 0);
    }
  }
  __syncthreads();  // Wq reads done; region0 becomes Qb/Xb
  // --- write Q (+bias) as bf16, plain [row][col] ---
#pragma unroll
  for (int ct = 0; ct < 8; ct++) {
    int col = ct * 16 + lrow;
    float bv = qbias[col];
#pragma unroll
    for (int reg = 0; reg < 4; reg++) {
      int lr = wv * 16 + quad * 4 + reg;
      Qb[(size_t)lr * 128 + col] = f2bf(acc[ct][reg] + bv);
    }
  }
  __syncthreads();
  // --- gather-mean: X[node] = mean_e relu(P[src_e] + Q[node]) -> Xb (swizzled) ---
#pragma unroll
  for (int it = 0; it < 4; it++) {
    int task = it * 256 + tid;
    int nl = task >> 4, g = task & 15;
    int node = bm + nl;
    if (node >= rows) continue;
    int c8 = g << 3;
    float q[8];
    {
      uint4 qv = *(const uint4*)(Qb + (size_t)nl * 128 + c8);
      unsigned qq[4] = {qv.x, qv.y, qv.z, qv.w};
#pragma unroll
      for (int k = 0; k < 4; k++) {
        q[2 * k] = __uint_as_float(qq[k] << 16);
        q[2 * k + 1] = __uint_as_float(qq[k] & 0xffff0000u);
      }
    }
    float acg[8] = {0.f, 0.f, 0.f, 0.f, 0.f, 0.f, 0.f, 0.f};
    int o = off[node], n = cnt[node];
    int i = 0;
    for (; i + 4 <= n; i += 4) {
      int s0 = srcs[o + i], s1 = srcs[o + i + 1], s2 = srcs[o + i + 2], s3 = srcs[o + i + 3];
      uint4 v0 = *(const uint4*)(P + (size_t)s0 * 128 + c8);
      uint4 v1 = *(const uint4*)(P + (size_t)s1 * 128 + c8);
      uint4 v2 = *(const uint4*)(P + (size_t)s2 * 128 + c8);
      uint4 v3 = *(const uint4*)(P + (size_t)s3 * 128 + c8);
      unsigned w[16] = {v0.x, v0.y, v0.z, v0.w, v1.x, v1.y, v1.z, v1.w,
                        v2.x, v2.y, v2.z, v2.w, v3.x, v3.y, v3.z, v3.w};
#pragma unroll
      for (int e = 0; e < 4; e++)
#pragma unroll
        for (int k = 0; k < 4; k++) {
          unsigned ww = w[e * 4 + k];
          float lo = __uint_as_float(ww << 16);
          float hi = __uint_as_float(ww & 0xffff0000u);
          acg[2 * k] += fmaxf(lo + q[2 * k], 0.f);
          acg[2 * k + 1] += fmaxf(hi + q[2 * k + 1], 0.f);
        }
    }
    for (; i < n; i++) {
      int s0 = srcs[o + i];
      uint4 v0 = *(const uint4*)(P + (size_t)s0 * 128 + c8);
      unsigned w[4] = {v0.x, v0.y, v0.z, v0.w};
#pragma unroll
      for (int k = 0; k < 4; k++) {
        unsigned ww = w[k];
        float lo = __uint_as_float(ww << 16);
        float hi = __uint_as_float(ww & 0xffff0000u);
        acg[2 * k] += fmaxf(lo + q[2 * k], 0.f);
        acg[2 * k + 1] += fmaxf(hi + q[2 * k + 1], 0.f);
      }
    }
    float inv = 1.f / fmaxf((float)n, 1.f);
    bf16x8 ov;
#pragma unroll
    for (int k = 0; k < 8; k++) ov[k] = (short)f2bf(acg[k] * inv);
    *(bf16x8*)(Xb + (size_t)nl * 128 + ((g ^ (nl & 15)) * 8)) = ov;
  }
  __syncthreads();
  // --- x A-frags from Xb ---
  bf16x8 ax[4];
#pragma unroll
  for (int ks = 0; ks < 4; ks++)
    ax[ks] = *(const bf16x8*)(Xb + (size_t)(wv * 16 + lrow) * 128 + (((ks * 4 + quad) ^ lrow) * 8));
  const int lr0 = wv * 16 + quad * 4;
  // --- GRU chunk loop (Wg overlays dead Qb/Xb) ---
  for (int ch = 0; ch < 8; ch++) {
    __syncthreads();  // ch=0: ax/Qb reads done; ch>0: prev Wg reads done
#pragma unroll
    for (int p = 0; p < 2; p++) {
      uint4 v[3];
#pragma unroll
      for (int j = 0; j < 3; j++) {
        int task = (p * 3 + j) * 256 + tid;
        int seg = task >> 8, rem = task & 255;
        int col = rem >> 4, gr = rem & 15;
        const u16* gsrc = (seg < 3 ? Wxb : Whb) +
                          (size_t)((seg < 3 ? seg : seg - 3) * 128 + ch * 16 + col) * 128 + gr * 8;
        v[j] = *(const uint4*)gsrc;
      }
#pragma unroll
      for (int j = 0; j < 3; j++) {
        int task = (p * 3 + j) * 256 + tid;
        int seg = task >> 8, rem = task & 255;
        int col = rem >> 4, gr = rem & 15;
        *(uint4*)(Wg + (size_t)(seg * 16 + col) * 128 + ((gr ^ col) * 8)) = v[j];
      }
    }
    __syncthreads();
    floatx4 gacc[3][2];
#pragma unroll
    for (int g = 0; g < 3; g++) {
      gacc[g][0] = {0.f, 0.f, 0.f, 0.f};
      gacc[g][1] = {0.f, 0.f, 0.f, 0.f};
    }
#pragma unroll
    for (int ks = 0; ks < 4; ks++) {
      int posu = ((4 * ks + quad) ^ lrow) * 8;
#pragma unroll
      for (int g = 0; g < 3; g++) {
        bf16x8 bx = *(const bf16x8*)(Wg + (size_t)(g * 16 + lrow) * 128 + posu);
        bf16x8 bh = *(const bf16x8*)(Wg + (size_t)((3 + g) * 16 + lrow) * 128 + posu);
        gacc[g][0] = __builtin_amdgcn_mfma_f32_16x16x32_bf16(ax[ks], bx, gacc[g][0], 0, 0, 0);
        gacc[g][1] = __builtin_amdgcn_mfma_f32_16x16x32_bf16(ah[ks], bh, gacc[g][1], 0, 0, 0);
      }
    }
    int hcol = ch * 16 + lrow;
    float bxz = gbias[hcol];
    float bxr = gbias[128 + hcol];
    float bxh = gbias[256 + hcol];
    float bhz = gbias[384 + hcol];
    float bhr = gbias[384 + 128 + hcol];
    float bhh = gbias[384 + 256 + hcol];
    int ggr = 2 * ch + (lrow >> 3);
    int gel = lrow & 7;
#pragma unroll
    for (int reg = 0; reg < 4; reg++) {
      int lr = lr0 + reg;
      float xz = gacc[0][0][reg] + bxz;
      float xr = gacc[1][0][reg] + bxr;
      float xh = gacc[2][0][reg] + bxh;
      float hz = gacc[0][1][reg] + bhz;
      float hr = gacc[1][1][reg] + bhr;
      float hh = gacc[2][1][reg] + bhh;
      float z = fsigmoid(xz + hz);
      float rr = fsigmoid(xr + hr);
      float hc = ftanh(xh + rr * hh);
      u16* hp = Hls + (size_t)lr * 128 + ((ggr ^ (lr & 15)) * 8) + gel;
      float hold = bf2f(*hp);
      *hp = f2bf(z * hold + (1.f - z) * hc);
    }
  }
  __syncthreads();
  // --- coalesced state write-out ---
#pragma unroll
  for (int i = 0; i < 4; i++) {
    int task = i * 256 + tid;
    int row = task >> 4, g = task & 15;
    int grow = bm + row;
    if (grow < rows)
      *(uint4*)(H + (size_t)grow * 128 + g * 8) =
          *(const uint4*)(Hls + (size_t)row * 128 + ((g ^ (row & 15)) * 8));
  }
}

// ---------------- fully fused readout: 2 GEMMs + logits + softmax ----------------
__global__ __launch_bounds__(256) void k_readout2(
    const u16* __restrict__ S, const u16* __restrict__ W1b, const float* __restrict__ b1,
    const u16* __restrict__ W2b, const float* __restrict__ b2,
    const float* __restrict__ W3, const float* __restrict__ b3,
    float* __restrict__ out, int M) {
  __shared__ __align__(16) char smem[64 * 132 * 4];  // 33792 B
  u16* Wls = (u16*)smem;
  u16* H1ls = (u16*)smem;
  u16* W2ls = (u16*)(smem + 17408);
  u16* H2ls = (u16*)smem;
  float* W3ls = (float*)(smem + 9216);
  float* b3ls = (float*)(smem + 9216 + 3840);
  const int tid = threadIdx.x, wv = tid >> 6, lane = tid & 63;
  const int lrow = lane & 15, quad = lane >> 4;
  const int bm = blockIdx.x * 64;
#pragma unroll
  for (int i = 0; i < 8; i++) {
    int task = i * 256 + tid;
    int col = task >> 4, gr = task & 15;
    uint4 v = *(const uint4*)(W1b + (size_t)col * 128 + gr * 8);
    *(uint4*)(Wls + (size_t)col * 128 + ((gr ^ (col & 15)) * 8)) = v;
  }
  const int arow = bm + wv * 16 + lrow;
  const bool arv = arow < M;
  const bf16x8 zv = {0, 0, 0, 0, 0, 0, 0, 0};
  bf16x8 a[4];
#pragma unroll
  for (int ks = 0; ks < 4; ks++)
    a[ks] = arv ? *(const bf16x8*)(S + (size_t)arow * 128 + quad * 8 + ks * 32) : zv;
  __syncthreads();
  floatx4 acc1[8];
#pragma unroll
  for (int ct = 0; ct < 8; ct++) acc1[ct] = {0.f, 0.f, 0.f, 0.f};
#pragma unroll
  for (int ks = 0; ks < 4; ks++) {
#pragma unroll
    for (int ct = 0; ct < 8; ct++) {
      int col = ct * 16 + lrow;
      bf16x8 b = *(const bf16x8*)(Wls + (size_t)col * 128 + (((4 * ks + quad) ^ lrow) * 8));
      acc1[ct] = __builtin_amdgcn_mfma_f32_16x16x32_bf16(a[ks], b, acc1[ct], 0, 0, 0);
    }
  }
  __syncthreads();
#pragma unroll
  for (int ct = 0; ct < 8; ct++) {
    int col = ct * 16 + lrow;
    float bv = b1[col];
#pragma unroll
    for (int reg = 0; reg < 4; reg++) {
      int lr = wv * 16 + quad * 4 + reg;
      H1ls[(size_t)lr * 136 + col] = f2bf(fmaxf(acc1[ct][reg] + bv, 0.f));
    }
  }
#pragma unroll
  for (int i = 0; i < 4; i++) {
    int task = i * 256 + tid;
    int col = task >> 4, gr = task & 15;
    uint4 v = *(const uint4*)(W2b + (size_t)col * 128 + gr * 8);
    *(uint4*)(W2ls + (size_t)col * 128 + ((gr ^ (col & 15)) * 8)) = v;
  }
  __syncthreads();
  bf16x8 a2[4];
#pragma unroll
  for (int ks = 0; ks < 4; ks++)
    a2[ks] = *(const bf16x8*)(H1ls + (size_t)(wv * 16 + lrow) * 136 + quad * 8 + ks * 32);
  floatx4 acc2[4];
#pragma unroll
  for (int ct = 0; ct < 4; ct++) acc2[ct] = {0.f, 0.f, 0.f, 0.f};
#pragma unroll
  for (int ks = 0; ks < 4; ks++) {
#pragma unroll
    for (int ct = 0; ct < 4; ct++) {
      int col = ct * 16 + lrow;
      bf16x8 b = *(const bf16x8*)(W2ls + (size_t)col * 128 + (((4 * ks + quad) ^ lrow) * 8));
      acc2[ct] = __builtin_amdgcn_mfma_f32_16x16x32_bf16(a2[ks], b, acc2[ct], 0, 0, 0);
    }
  }
  __syncthreads();
#pragma unroll
  for (int ct = 0; ct < 4; ct++) {
    int col = ct * 16 + lrow;
    float bv = b2[col];
#pragma unroll
    for (int reg = 0; reg < 4; reg++) {
      int lr = wv * 16 + quad * 4 + reg;
      H2ls[(size_t)lr * 72 + col] = f2bf(fmaxf(acc2[ct][reg] + bv, 0.f));
    }
  }
  for (int l = tid; l < 960; l += 256) W3ls[l] = W3[l];
  if (tid < 15) b3ls[tid] = b3[tid];
  __syncthreads();
  if (tid < 64) {
    int row = tid, gr2 = bm + row;
    if (gr2 < M) {
      float lg[15];
#pragma unroll
      for (int c = 0; c < 15; c++) lg[c] = b3ls[c];
      for (int k = 0; k < 64; k++) {
        float hk = bf2f(H2ls[(size_t)row * 72 + k]);
#pragma unroll
        for (int c = 0; c < 15; c++) lg[c] += hk * W3ls[k * 15 + c];
      }
      float m = lg[0];
#pragma unroll
      for (int c = 1; c < 15; c++) m = fmaxf(m, lg[c]);
      float ssum = 0.f;
#pragma unroll
      for (int c = 0; c < 15; c++) { lg[c] = __expf(lg[c] - m); ssum += lg[c]; }
      float inv = 1.f / ssum;
#pragma unroll
      for (int c = 0; c < 15; c++) out[(size_t)gr2 * 15 + c] = lg[c] * inv;
    }
  }
}

// ---------------- launch ----------------
extern "C" void kernel_launch(void* const* d_in, const int* in_sizes, int n_in,
                              void* d_out, int out_size, void* d_ws, size_t ws_size,
                              hipStream_t stream) {
  const float* feat = (const float*)d_in[0];
  const int* src1 = (const int*)d_in[1];
  const int* dst1 = (const int*)d_in[2];
  const int* src2 = (const int*)d_in[3];
  const int* dst2 = (const int*)d_in[4];
  const float* Wm1 = (const float*)d_in[5];
  const float* bm1 = (const float*)d_in[6];
  const float* Wm2 = (const float*)d_in[7];
  const float* bm2 = (const float*)d_in[8];
  const float* gik = (const float*)d_in[9];
  const float* gir = (const float*)d_in[10];
  const float* gib = (const float*)d_in[11];
  const float* gck = (const float*)d_in[12];
  const float* gcr = (const float*)d_in[13];
  const float* gcb = (const float*)d_in[14];
  const float* Wr1 = (const float*)d_in[15];
  const float* br1 = (const float*)d_in[16];
  const float* Wr2 = (const float*)d_in[17];
  const float* br2 = (const float*)d_in[18];
  const float* Wr3 = (const float*)d_in[19];
  const float* br3 = (const float*)d_in[20];
  float* out = (float*)d_out;

  // ---- workspace layout (u16 units) ----
  u16* w16 = (u16*)d_ws;
  size_t o = 0;
  u16* ip_state = w16 + o;   o += (size_t)N_IP * D;
  u16* conn_state = w16 + o; o += (size_t)N_CONN * D;
  u16* P1 = w16 + o;         o += (size_t)N_IP * D;
  u16* P2 = w16 + o;         o += (size_t)N_CONN * D;
  u16* gikb = w16 + o;       o += 49152;
  u16* girb = w16 + o;       o += 49152;
  u16* gckb = w16 + o;       o += 49152;
  u16* gcrb = w16 + o;       o += 49152;
  u16* wm1b = w16 + o;       o += 16384;
  u16* wm2b = w16 + o;       o += 16384;
  u16* wm1t = w16 + o;       o += 16384;
  u16* wm2t = w16 + o;       o += 16384;
  u16* wr1b = w16 + o;       o += 16384;
  u16* wr2b = w16 + o;       o += 8192;
  int* ip = (int*)(w16 + o);
  int* cnt1 = ip;  ip += N_CONN;
  int* cnt2 = ip;  ip += N_IP;
  int* off1 = ip;  ip += N_CONN;
  int* off2 = ip;  ip += N_IP;
  int* cur1 = ip;  ip += N_CONN;
  int* cur2 = ip;  ip += N_IP;
  int* srcs1 = ip; ip += NE;
  int* srcs2 = ip; ip += NE;
  int* bsum1 = ip; ip += 256;
  int* bsum2 = ip; ip += 256;

  const int BT = 256;

  // ---- fused init + weight prep ----
  const int nstate = (N_IP + N_CONN) * D;
  k_init_all<<<(nstate + BT - 1) / BT, BT, 0, stream>>>(ip_state, conn_state, feat, cnt1);
  k_prep_all<<<(286720 + BT - 1) / BT, BT, 0, stream>>>(
      gik, gir, gck, gcr, Wm1, Wm2, Wr1, Wr2,
      gikb, girb, gckb, gcrb, wm1b, wm2b, wm1t, wm2t, wr1b, wr2b);

  // ---- build CSR ----
  k_count<<<(NE + BT - 1) / BT, BT, 0, stream>>>(dst1, dst2, cnt1, cnt2);
  const int nb1 = (N_CONN + 1023) / 1024, nb2 = (N_IP + 1023) / 1024;
  k_scan_part2<<<nb1 + nb2, 256, 0, stream>>>(cnt1, bsum1, N_CONN, nb1, cnt2, bsum2, N_IP);
  k_scan_mid2<<<1, 256, 0, stream>>>(bsum1, nb1, bsum2, nb2);
  k_scan_final2<<<nb1 + nb2, 256, 0, stream>>>(cnt1, bsum1, off1, cur1, N_CONN, nb1,
                                               cnt2, bsum2, off2, cur2, N_IP);
  k_scatter<<<(NE + BT - 1) / BT, BT, 0, stream>>>(src1, dst1, src2, dst2,
                                                   cur1, cur2, srcs1, srcs2);

  const int t64ip = (N_IP + 63) / 64;       // 313
  const int t64cn = (N_CONN + 63) / 64;     // 1563

  for (int t = 0; t < T_ROUNDS; t++) {
    // P1 = old ip_state @ Wm1_top; P2 = old conn_state @ Wm2_top
    k_gemmP<<<t64ip + t64cn, 256, 0, stream>>>(ip_state, wm1t, P1, N_IP, t64ip,
                                               conn_state, wm2t, P2, N_CONN);
    // fused Q-GEMM + gather-mean + GRU for both node types (states updated in place;
    // cross-type reads go through frozen P1/P2 only)
    k_msggru<<<t64cn + t64ip, 256, 0, stream>>>(
        conn_state, wm1b, bm1, P1, srcs1, off1, cnt1, gckb, gcrb, gcb, N_CONN, t64cn,
        ip_state, wm2b, bm2, P2, srcs2, off2, cnt2, gikb, girb, gib, N_IP);
  }

  k_readout2<<<t64cn, 256, 0, stream>>>(conn_state, wr1b, br1, wr2b, br2,
                                        Wr3, br3, out, N_CONN);
}